// Round 13
// baseline (1086.065 us; speedup 1.0000x reference)
//
#include <hip/hip_runtime.h>
#include <hip/hip_bf16.h>
#include <math.h>

// Mixtral decoder layer, MI355X. T=2048 H=2048 NH=16 NKV=4 HD=128 I=4096 E=8 TOPK=2.
// Pre-router path (QKV, attn, o_proj): 3-pass bf16-split MFMA (~fp32 accurate) so the
// router top-k matches the fp32 reference; MoE expert path is plain bf16.
// R13: w13 scaled to BM=256 / 8 waves (same proven 2-barrier gll16 skeleton) ->
// 1.5x FLOP per staged byte; scan granularity 256; w2k derives its 128-tiles from counts.

#define T_  2048
#define H_  2048
#define NH  16
#define NKV 4
#define HD  128
#define II_ 4096
#define NE  8
#define EPS 1e-5f
#define PROWS 6144   // padded permuted rows (256-granular)

typedef __bf16 bf16x8 __attribute__((ext_vector_type(8)));
typedef float  f32x4  __attribute__((ext_vector_type(4)));
typedef unsigned short u16;

__device__ __forceinline__ u16 f2b(float f){ __bf16 b = (__bf16)f; return __builtin_bit_cast(u16, b); }
__device__ __forceinline__ float b2f(u16 u){ return (float)__builtin_bit_cast(__bf16, u); }

__device__ __forceinline__ void gll16(const void* g, void* l){
  __builtin_amdgcn_global_load_lds(
      (const __attribute__((address_space(1))) unsigned int*)g,
      (__attribute__((address_space(3))) unsigned int*)l, 16, 0, 0);
}

// ---------------- fp32 -> split (hi, lo) bf16 conversion ----------------
__global__ __launch_bounds__(256) void mx_cvt_split(const float* __restrict__ s,
                                                    u16* __restrict__ hi,
                                                    u16* __restrict__ lo, int n8)
{
  int i = blockIdx.x*256 + threadIdx.x;
  int stride = gridDim.x*256;
  for (; i < n8; i += stride){
    const f32x4* p = (const f32x4*)s + 2*(size_t)i;
    f32x4 a = p[0], b = p[1];
    uint4 uh, ul;
    u16 h0,h1,h2,h3;
    h0=f2b(a[0]); h1=f2b(a[1]); h2=f2b(a[2]); h3=f2b(a[3]);
    uh.x = (unsigned)h0 | ((unsigned)h1<<16);
    uh.y = (unsigned)h2 | ((unsigned)h3<<16);
    ul.x = (unsigned)f2b(a[0]-b2f(h0)) | ((unsigned)f2b(a[1]-b2f(h1))<<16);
    ul.y = (unsigned)f2b(a[2]-b2f(h2)) | ((unsigned)f2b(a[3]-b2f(h3))<<16);
    h0=f2b(b[0]); h1=f2b(b[1]); h2=f2b(b[2]); h3=f2b(b[3]);
    uh.z = (unsigned)h0 | ((unsigned)h1<<16);
    uh.w = (unsigned)h2 | ((unsigned)h3<<16);
    ul.z = (unsigned)f2b(b[0]-b2f(h0)) | ((unsigned)f2b(b[1]-b2f(h1))<<16);
    ul.w = (unsigned)f2b(b[2]-b2f(h2)) | ((unsigned)f2b(b[3]-b2f(h3))<<16);
    ((uint4*)hi)[i] = uh;
    ((uint4*)lo)[i] = ul;
  }
}

// ---------------- RoPE cos/sin table (double-precision inv_freq) ----------------
__global__ void mx_rope_table(const int* __restrict__ pos, float* __restrict__ cosT,
                              float* __restrict__ sinT)
{
  int i = blockIdx.x*256 + threadIdx.x;            // T*64
  int t = i >> 6, d = i & 63;
  float inv = (float)exp(-((double)d/64.0) * 9.210340371976184); // 10000^{-d/64}
  float f = (float)pos[t] * inv;
  cosT[i] = cosf(f); sinT[i] = sinf(f);
}

// ---------------- fused add + RMSNorm (writes several output forms) ----------------
__global__ __launch_bounds__(256) void mx_addnorm(
    const float* __restrict__ a, const float* __restrict__ b,
    const float* __restrict__ gam, float* __restrict__ res_out,
    u16* __restrict__ hi, u16* __restrict__ lo,
    float* __restrict__ hf, u16* __restrict__ hbf, int* __restrict__ mz)
{
  int t = blockIdx.x, tid = threadIdx.x;
  if (mz && t == 0 && tid < 8) mz[tid] = 0;
  const float4* A4 = (const float4*)a + (size_t)t*512;
  const float4* B4 = (const float4*)b + (size_t)t*512;
  float4 va = A4[tid], vb = B4[tid];
  float4 x0; x0.x=va.x+vb.x; x0.y=va.y+vb.y; x0.z=va.z+vb.z; x0.w=va.w+vb.w;
  va = A4[tid+256]; vb = B4[tid+256];
  float4 x1; x1.x=va.x+vb.x; x1.y=va.y+vb.y; x1.z=va.z+vb.z; x1.w=va.w+vb.w;
  float ss = x0.x*x0.x + x0.y*x0.y + x0.z*x0.z + x0.w*x0.w
           + x1.x*x1.x + x1.y*x1.y + x1.z*x1.z + x1.w*x1.w;
  #pragma unroll
  for (int d=32; d; d>>=1) ss += __shfl_down(ss, d);
  __shared__ float red[4];
  if ((tid&63)==0) red[tid>>6] = ss;
  __syncthreads();
  ss = red[0]+red[1]+red[2]+red[3];
  float scale = rsqrtf(ss * (1.f/2048.f) + EPS);
  float4* R4 = (float4*)res_out + (size_t)t*512;
  R4[tid] = x0; R4[tid+256] = x1;
  const float4* G4p = (const float4*)gam;
  float4 g0 = G4p[tid], g1 = G4p[tid+256];
  float4 y0; y0.x=x0.x*scale*g0.x; y0.y=x0.y*scale*g0.y; y0.z=x0.z*scale*g0.z; y0.w=x0.w*scale*g0.w;
  float4 y1; y1.x=x1.x*scale*g1.x; y1.y=x1.y*scale*g1.y; y1.z=x1.z*scale*g1.z; y1.w=x1.w*scale*g1.w;
  if (hf){ float4* H4 = (float4*)hf + (size_t)t*512; H4[tid]=y0; H4[tid+256]=y1; }
  if (hi){
    ushort4 uh, ul;
    uh.x=f2b(y0.x); ul.x=f2b(y0.x-b2f(uh.x));
    uh.y=f2b(y0.y); ul.y=f2b(y0.y-b2f(uh.y));
    uh.z=f2b(y0.z); ul.z=f2b(y0.z-b2f(uh.z));
    uh.w=f2b(y0.w); ul.w=f2b(y0.w-b2f(uh.w));
    ((ushort4*)hi)[(size_t)t*512 + tid] = uh; ((ushort4*)lo)[(size_t)t*512 + tid] = ul;
    uh.x=f2b(y1.x); ul.x=f2b(y1.x-b2f(uh.x));
    uh.y=f2b(y1.y); ul.y=f2b(y1.y-b2f(uh.y));
    uh.z=f2b(y1.z); ul.z=f2b(y1.z-b2f(uh.z));
    uh.w=f2b(y1.w); ul.w=f2b(y1.w-b2f(uh.w));
    ((ushort4*)hi)[(size_t)t*512 + tid+256] = uh; ((ushort4*)lo)[(size_t)t*512 + tid+256] = ul;
  }
  if (hbf){
    ushort4 u0; u0.x=f2b(y0.x); u0.y=f2b(y0.y); u0.z=f2b(y0.z); u0.w=f2b(y0.w);
    ushort4 u1; u1.x=f2b(y1.x); u1.y=f2b(y1.y); u1.z=f2b(y1.z); u1.w=f2b(y1.w);
    ((ushort4*)hbf)[(size_t)t*512 + tid] = u0; ((ushort4*)hbf)[(size_t)t*512 + tid+256] = u1;
  }
}

// ------- 3-pass split GEMM, gll16 m97 skeleton: C = A(hi,lo) x B(hi,lo)^T, fp32 out -------
template<int NX, int NY>
__global__ __launch_bounds__(256,2) void mx_gemm3g(
    const u16* __restrict__ Ah, const u16* __restrict__ Al,
    const u16* __restrict__ Bh, const u16* __restrict__ Bl,
    float* __restrict__ C, int ldc, int K)
{
  __shared__ u16 AhS[128*64], AlS[128*64], BhS[128*64], BlS[128*64];
  int bid = blockIdx.x;
  int xcd = bid & 7, j = bid >> 3;
  int x = j % NX, p = j / NX;
  int y = xcd + 8*p;
  int m0 = x*128, n0 = y*128;
  int tid = threadIdx.x;
  int w = tid>>6, lane = tid&63, wr = w>>1, wc = w&1, g = lane>>4, lr = lane&15;
  f32x4 acc[4][4];
  #pragma unroll
  for (int fm=0;fm<4;fm++)
    #pragma unroll
    for (int fn=0;fn<4;fn++) acc[fm][fn] = (f32x4){0.f,0.f,0.f,0.f};

  for (int k0 = 0; k0 < K; k0 += 64) {
    #pragma unroll
    for (int i=0;i<4;i++){
      int c = i*256 + tid, r = c>>3, ch = c&7;
      int sw = ((ch ^ (r&7))<<3);
      int db = (i*256 + w*64)<<3;
      gll16(Ah + (size_t)(m0+r)*K + k0 + sw, &AhS[db]);
      gll16(Al + (size_t)(m0+r)*K + k0 + sw, &AlS[db]);
      gll16(Bh + (size_t)(n0+r)*K + k0 + sw, &BhS[db]);
      gll16(Bl + (size_t)(n0+r)*K + k0 + sw, &BlS[db]);
    }
    __syncthreads();
    #pragma unroll
    for (int kk=0;kk<2;kk++){
      bf16x8 ah[4], al[4], bh[4], bl[4];
      #pragma unroll
      for (int fm=0;fm<4;fm++){
        int r = wr*64 + fm*16 + lr;
        int ch = ((kk<<2)+g) ^ (r&7);
        ah[fm] = *(const bf16x8*)(&AhS[(r<<6)+(ch<<3)]);
        al[fm] = *(const bf16x8*)(&AlS[(r<<6)+(ch<<3)]);
      }
      #pragma unroll
      for (int fn=0;fn<4;fn++){
        int r = wc*64 + fn*16 + lr;
        int ch = ((kk<<2)+g) ^ (r&7);
        bh[fn] = *(const bf16x8*)(&BhS[(r<<6)+(ch<<3)]);
        bl[fn] = *(const bf16x8*)(&BlS[(r<<6)+(ch<<3)]);
      }
      __builtin_amdgcn_s_setprio(1);
      #pragma unroll
      for (int fm=0;fm<4;fm++)
        #pragma unroll
        for (int fn=0;fn<4;fn++){
          acc[fm][fn] = __builtin_amdgcn_mfma_f32_16x16x32_bf16(ah[fm], bh[fn], acc[fm][fn],0,0,0);
          acc[fm][fn] = __builtin_amdgcn_mfma_f32_16x16x32_bf16(ah[fm], bl[fn], acc[fm][fn],0,0,0);
          acc[fm][fn] = __builtin_amdgcn_mfma_f32_16x16x32_bf16(al[fm], bh[fn], acc[fm][fn],0,0,0);
        }
      __builtin_amdgcn_s_setprio(0);
    }
    __syncthreads();
  }
  #pragma unroll
  for (int fm=0;fm<4;fm++)
    #pragma unroll
    for (int fn=0;fn<4;fn++)
      #pragma unroll
      for (int i=0;i<4;i++){
        size_t rg = (size_t)(m0 + wr*64 + fm*16 + g*4 + i);
        int cg = n0 + wc*64 + fn*16 + lr;
        C[rg*ldc + cg] = acc[fm][fn][i];
      }
}

// ------------- MoE w1+w3 fused GEMM + silu epilogue, BM=256 / 8 waves -------------
// Same 2-barrier gll16 single-buffer skeleton, scaled: stages 64KB LDS per K-step for
// 512 wave-MFMAs (vs 48KB/256). 2 blocks/CU at 64KB LDS + 512 threads.
template<int NY>
__global__ __launch_bounds__(512,2) void mx_moe_w13(
    const u16* __restrict__ A,
    const u16* __restrict__ B1, const u16* __restrict__ B3,
    u16* __restrict__ Y,
    const int* __restrict__ row_map, const int* __restrict__ meta)
{
  __shared__ u16 As[256*64], B1s[128*64], B3s[128*64];   // 32+16+16 = 64 KB
  int bid = blockIdx.x;
  int xcd = bid & 7, j = bid >> 3;
  int x = j & 7, p = j >> 3;
  int panel = xcd + 8*p;                 // < NE*NY
  int e = panel / NY, y = panel % NY;
  if (x >= meta[16+e]) return;           // ptiles (256-granular)
  int rowbase = meta[8+e] + (x<<8);
  const u16* B1p = B1 + ((size_t)e*II_ + y*128)*H_;
  const u16* B3p = B3 + ((size_t)e*II_ + y*128)*H_;
  int tid = threadIdx.x;
  int w = tid>>6, lane = tid&63, wr = w>>1, wc = w&1, g = lane>>4, lr = lane&15;

  // staging sources (gather + swizzle resolved once)
  const u16 *sA[4]; int dA[4];
  #pragma unroll
  for (int i=0;i<4;i++){
    int c = i*512 + tid, r = c>>3, ch = c&7;
    sA[i] = A + (size_t)row_map[rowbase + r]*H_ + ((ch ^ (r&7))<<3);
    dA[i] = (i*512 + w*64)<<3;
  }
  const u16 *sB1[2], *sB3[2]; int dB[2];
  #pragma unroll
  for (int i=0;i<2;i++){
    int c = i*512 + tid, r = c>>3, ch = c&7;
    int sw = (ch ^ (r&7))<<3;
    sB1[i] = B1p + (size_t)r*H_ + sw;
    sB3[i] = B3p + (size_t)r*H_ + sw;
    dB[i] = (i*512 + w*64)<<3;
  }

  f32x4 acc1[4][4], acc3[4][4];
  #pragma unroll
  for (int fm=0;fm<4;fm++)
    #pragma unroll
    for (int fn=0;fn<4;fn++){ acc1[fm][fn]=(f32x4){0,0,0,0}; acc3[fm][fn]=(f32x4){0,0,0,0}; }

  for (int k0 = 0; k0 < H_; k0 += 64) {
    #pragma unroll
    for (int i=0;i<4;i++) gll16(sA[i] + k0, &As[dA[i]]);
    #pragma unroll
    for (int i=0;i<2;i++){
      gll16(sB1[i] + k0, &B1s[dB[i]]);
      gll16(sB3[i] + k0, &B3s[dB[i]]);
    }
    __syncthreads();
    #pragma unroll
    for (int kk=0;kk<2;kk++){
      bf16x8 af[4], b1f[4], b3f[4];
      #pragma unroll
      for (int fm=0;fm<4;fm++){
        int r = wr*64 + fm*16 + lr;
        int ch = ((kk<<2)+g) ^ (r&7);
        af[fm] = *(const bf16x8*)(&As[(r<<6)+(ch<<3)]);
      }
      #pragma unroll
      for (int fn=0;fn<4;fn++){
        int r = wc*64 + fn*16 + lr;
        int ch = ((kk<<2)+g) ^ (r&7);
        b1f[fn] = *(const bf16x8*)(&B1s[(r<<6)+(ch<<3)]);
        b3f[fn] = *(const bf16x8*)(&B3s[(r<<6)+(ch<<3)]);
      }
      __builtin_amdgcn_s_setprio(1);
      #pragma unroll
      for (int fm=0;fm<4;fm++)
        #pragma unroll
        for (int fn=0;fn<4;fn++){
          acc1[fm][fn] = __builtin_amdgcn_mfma_f32_16x16x32_bf16(af[fm], b1f[fn], acc1[fm][fn],0,0,0);
          acc3[fm][fn] = __builtin_amdgcn_mfma_f32_16x16x32_bf16(af[fm], b3f[fn], acc3[fm][fn],0,0,0);
        }
      __builtin_amdgcn_s_setprio(0);
    }
    __syncthreads();
  }
  // wr spans 4x64 = 256 rows; wc spans 2x64 = 128 cols
  int n0 = y*128 + wc*64;
  #pragma unroll
  for (int fm=0;fm<4;fm++)
    #pragma unroll
    for (int fn=0;fn<4;fn++)
      #pragma unroll
      for (int i=0;i<4;i++){
        size_t rg = (size_t)(rowbase + wr*64 + fm*16 + g*4 + i);
        int cg = n0 + fn*16 + lr;
        float gg = acc1[fm][fn][i], uu = acc3[fm][fn][i];
        float sg = gg / (1.f + __expf(-gg));
        Y[rg*II_ + cg] = f2b(sg * uu);
      }
}

// ------------- MoE w2 GEMM (all-bf16, m97-style 128x128): Y2 = Y . w2^T -------------
// Tile count derived from counts (scan granularity is 256 now).
template<int NY>
__global__ __launch_bounds__(256,2) void mx_moe_w2k(
    const u16* __restrict__ A,       // Y bf16 [PROWS][II_]
    const u16* __restrict__ B,       // w2b bf16 [E][H_][II_]
    float* __restrict__ C,           // Y2 fp32 [PROWS][H_]
    const int* __restrict__ meta)
{
  __shared__ u16 As[128*64], Bs[128*64];
  int bid = blockIdx.x;
  int xcd = bid & 7, j = bid >> 3;
  int x = j & 15, p = j >> 4;
  int panel = xcd + 8*p;                 // < NE*NY
  int e = panel / NY, y = panel % NY;
  if (x >= ((meta[e] + 127) >> 7)) return;   // 128-granular tiles from counts
  int rowbase = meta[8+e] + (x<<7);
  const u16* Bp = B + ((size_t)e*H_ + y*128)*II_;
  int tid = threadIdx.x;
  int w = tid>>6, lane = tid&63, wr = w>>1, wc = w&1, g = lane>>4, lr = lane&15;

  f32x4 acc[4][4];
  #pragma unroll
  for (int fm=0;fm<4;fm++)
    #pragma unroll
    for (int fn=0;fn<4;fn++) acc[fm][fn] = (f32x4){0,0,0,0};

  for (int k0 = 0; k0 < II_; k0 += 64) {
    #pragma unroll
    for (int i=0;i<4;i++){
      int c = i*256 + tid, r = c>>3, ch = c&7;
      int sw = (ch ^ (r&7))<<3;
      int db = (i*256 + w*64)<<3;
      gll16(A  + (size_t)(rowbase + r)*II_ + k0 + sw, &As[db]);
      gll16(Bp + (size_t)r*II_             + k0 + sw, &Bs[db]);
    }
    __syncthreads();
    #pragma unroll
    for (int kk=0;kk<2;kk++){
      bf16x8 af[4], bf[4];
      #pragma unroll
      for (int fm=0;fm<4;fm++){
        int r = wr*64 + fm*16 + lr;
        int ch = ((kk<<2)+g) ^ (r&7);
        af[fm] = *(const bf16x8*)(&As[(r<<6)+(ch<<3)]);
      }
      #pragma unroll
      for (int fn=0;fn<4;fn++){
        int r = wc*64 + fn*16 + lr;
        int ch = ((kk<<2)+g) ^ (r&7);
        bf[fn] = *(const bf16x8*)(&Bs[(r<<6)+(ch<<3)]);
      }
      __builtin_amdgcn_s_setprio(1);
      #pragma unroll
      for (int fm=0;fm<4;fm++)
        #pragma unroll
        for (int fn=0;fn<4;fn++)
          acc[fm][fn] = __builtin_amdgcn_mfma_f32_16x16x32_bf16(af[fm], bf[fn], acc[fm][fn],0,0,0);
      __builtin_amdgcn_s_setprio(0);
    }
    __syncthreads();
  }
  int n0 = y*128 + wc*64;
  #pragma unroll
  for (int fm=0;fm<4;fm++)
    #pragma unroll
    for (int fn=0;fn<4;fn++)
      #pragma unroll
      for (int i=0;i<4;i++){
        size_t rg = (size_t)(rowbase + wr*64 + fm*16 + g*4 + i);
        int cg = n0 + fn*16 + lr;
        C[rg*H_ + cg] = acc[fm][fn][i];
      }
}

// ---------------- RoPE apply: qkv fp32 -> split-bf16 Q [h][t][d], K [kv][t][d] ----------------
__global__ __launch_bounds__(256) void mx_rope_apply(const float* __restrict__ qkv,
    const float* __restrict__ cosT, const float* __restrict__ sinT,
    u16* __restrict__ qh, u16* __restrict__ ql, u16* __restrict__ kh, u16* __restrict__ kl)
{
  int t = blockIdx.x*4 + (threadIdx.x>>6);
  int hh = blockIdx.y, d = threadIdx.x & 63;
  const float* row = qkv + (size_t)t*3072;
  float c = cosT[t*64+d], s = sinT[t*64+d];
  float x1, x2; size_t base; u16 *oh, *ol;
  if (hh < NH){ x1 = row[hh*HD+d]; x2 = row[hh*HD+d+64];
     base = ((size_t)hh*T_ + t)*HD; oh = qh; ol = ql; }
  else { int kvh = hh-NH; x1 = row[2048 + kvh*HD + d]; x2 = row[2048 + kvh*HD + d + 64];
     base = ((size_t)kvh*T_ + t)*HD; oh = kh; ol = kl; }
  float o1 = x1*c - x2*s, o2 = x2*c + x1*s;
  u16 a = f2b(o1); oh[base+d]    = a; ol[base+d]    = f2b(o1 - b2f(a));
  u16 b = f2b(o2); oh[base+d+64] = b; ol[base+d+64] = f2b(o2 - b2f(b));
}

// ---------------- V transpose: qkv fp32 -> split-bf16 V^T [kv][d][t] ----------------
__global__ void mx_transpose_v(const float* __restrict__ qkv,
                               u16* __restrict__ vh, u16* __restrict__ vl)
{
  __shared__ float tile[64][132];
  int kv = blockIdx.x, t0 = blockIdx.y*64, tid = threadIdx.x;
  #pragma unroll
  for (int it=0; it<32; ++it){
    int idx = it*256 + tid; int r = idx>>7, d = idx&127;
    tile[r][d] = qkv[(size_t)(t0+r)*3072 + 2560 + kv*HD + d];
  }
  __syncthreads();
  #pragma unroll
  for (int it=0; it<32; ++it){
    int idx = it*256 + tid; int d = idx>>6, j = idx&63;
    float x = tile[j][d];
    u16 a = f2b(x);
    size_t o = ((size_t)kv*HD + d)*T_ + t0 + j;
    vh[o] = a; vl[o] = f2b(x - b2f(a));
  }
}

// ---------------- flash attention (y<8) + weight-cvt helper blocks (y>=8) ----------------
__global__ __launch_bounds__(512) void mx_attn(
  const u16* __restrict__ qh_, const u16* __restrict__ ql_,
  const u16* __restrict__ kh_, const u16* __restrict__ kl_,
  const u16* __restrict__ vh_, const u16* __restrict__ vl_,
  u16* __restrict__ oh_, u16* __restrict__ ol_,
  const float* __restrict__ w1f, const float* __restrict__ w3f,
  const float* __restrict__ w2f,
  u16* __restrict__ w1b, u16* __restrict__ w3b, u16* __restrict__ w2b)
{
  if (blockIdx.y >= 8){
    // -------- cvt helper path (no LDS, no barriers) --------
    const int n8 = NE*II_*H_/8;                       // 8388608 per matrix
    int hb = (blockIdx.y - 8)*gridDim.x + blockIdx.x; // 0..3839
    int i  = hb*512 + threadIdx.x;
    const int stride = 3840*512;
    for (; i < 3*n8; i += stride){
      const float* s; u16* d; int j;
      if (i < n8)        { s = w1f; d = w1b; j = i; }
      else if (i < 2*n8) { s = w3f; d = w3b; j = i - n8; }
      else               { s = w2f; d = w2b; j = i - 2*n8; }
      const f32x4* p = (const f32x4*)s + 2*(size_t)j;
      f32x4 a = p[0], b = p[1];
      uint4 u;
      u.x = (unsigned)f2b(a[0]) | ((unsigned)f2b(a[1])<<16);
      u.y = (unsigned)f2b(a[2]) | ((unsigned)f2b(a[3])<<16);
      u.z = (unsigned)f2b(b[0]) | ((unsigned)f2b(b[1])<<16);
      u.w = (unsigned)f2b(b[2]) | ((unsigned)f2b(b[3])<<16);
      ((uint4*)d)[j] = u;
    }
    return;
  }

  int pair = blockIdx.y;                    // 0..7 -> heads (2p, 2p+1)
  int kvh = pair >> 1;
  int qt = (pair & 4) ? (31 - (int)blockIdx.x) : (int)blockIdx.x;
  int tid = threadIdx.x, w = tid>>6, lane = tid&63, g = lane>>4, lr = lane&15;
  int head = pair*2 + (w>>2);
  int q0 = qt*64 + (w&3)*16;
  __shared__ u16 KV[2][4][8192];            // [buf][Kh,Kl,Vh,Vl] 128 KB
  __shared__ u16 Ph[8][1024], Pl[8][1024];  // 32 KB (per-wave)

  bf16x8 qfh[4], qfl[4];
  const u16* qrh = qh_ + ((size_t)head*T_ + q0 + lr)*HD;
  const u16* qrl = ql_ + ((size_t)head*T_ + q0 + lr)*HD;
  #pragma unroll
  for (int kk=0;kk<4;kk++){
    qfh[kk] = *(const bf16x8*)(qrh + kk*32 + g*8);
    qfl[kk] = *(const bf16x8*)(qrl + kk*32 + g*8);
  }
  f32x4 o[8];
  #pragma unroll
  for (int nf=0;nf<8;nf++) o[nf] = (f32x4){0.f,0.f,0.f,0.f};
  float mreg[4] = {-3e38f,-3e38f,-3e38f,-3e38f}, lsum[4] = {0.f,0.f,0.f,0.f};

  const u16* kbase = kh_ + (size_t)kvh*T_*HD;
  const u16* lbase = kl_ + (size_t)kvh*T_*HD;
  const u16* vbase = vh_ + (size_t)kvh*HD*T_;
  const u16* wbase = vl_ + (size_t)kvh*HD*T_;

  auto stage = [&](int buf, int kvb){
    #pragma unroll
    for (int i=0;i<2;i++){
      int cb = i*512 + w*64;                // wave-uniform chunk base (0..1023)
      int c  = cb + lane;
      int kr = c>>4, kc = ((c&15) ^ (kr&7))<<3;
      gll16(kbase + (size_t)(kvb+kr)*HD + kc, &KV[buf][0][cb*8]);
      gll16(lbase + (size_t)(kvb+kr)*HD + kc, &KV[buf][1][cb*8]);
      int vr = c>>3, vc = ((c&7) ^ (vr&7))<<3;
      gll16(vbase + (size_t)vr*T_ + kvb + vc, &KV[buf][2][cb*8]);
      gll16(wbase + (size_t)vr*T_ + kvb + vc, &KV[buf][3][cb*8]);
    }
  };

  stage(0, 0);      // prologue: 8 loads/thread in flight

  for (int kt = 0; kt <= qt; ++kt) {
    int cur = kt & 1;
    int kvb = kt*64;
    if (kt < qt) {
      stage(cur^1, kvb+64);
      asm volatile("s_waitcnt vmcnt(8)" ::: "memory");   // cur tile landed, next in flight
    } else {
      asm volatile("s_waitcnt vmcnt(0)" ::: "memory");
    }
    __builtin_amdgcn_s_barrier();

    // ---- QK^T (3-pass split) from LDS ----
    f32x4 s[4];
    #pragma unroll
    for (int nf=0;nf<4;nf++) s[nf] = (f32x4){0.f,0.f,0.f,0.f};
    __builtin_amdgcn_s_setprio(1);
    #pragma unroll
    for (int nf=0; nf<4; nf++){
      int row = nf*16 + lr;
      #pragma unroll
      for (int kk=0;kk<4;kk++){
        int off = row*128 + ((((kk<<2)+g) ^ (lr&7))<<3);
        bf16x8 kf = *(const bf16x8*)(&KV[cur][0][off]);
        bf16x8 kg = *(const bf16x8*)(&KV[cur][1][off]);
        s[nf] = __builtin_amdgcn_mfma_f32_16x16x32_bf16(qfh[kk], kf, s[nf],0,0,0);
        s[nf] = __builtin_amdgcn_mfma_f32_16x16x32_bf16(qfh[kk], kg, s[nf],0,0,0);
        s[nf] = __builtin_amdgcn_mfma_f32_16x16x32_bf16(qfl[kk], kf, s[nf],0,0,0);
      }
    }
    __builtin_amdgcn_s_setprio(0);

    // ---- online softmax ----
    float sv[4][4], pm[4];
    #pragma unroll
    for (int i=0;i<4;i++) pm[i] = -3e38f;
    bool diag = (kt == qt);
    #pragma unroll
    for (int nf=0;nf<4;nf++)
      #pragma unroll
      for (int i=0;i<4;i++){
        float v = s[nf][i] * 0.08838834764831845f;
        if (diag && (kvb + nf*16 + lr > q0 + g*4 + i)) v = -1e30f;
        sv[nf][i] = v;
        pm[i] = fmaxf(pm[i], v);
      }
    #pragma unroll
    for (int i=0;i<4;i++)
      #pragma unroll
      for (int d=1; d<16; d<<=1) pm[i] = fmaxf(pm[i], __shfl_xor(pm[i], d));
    float sf[4], psum[4];
    #pragma unroll
    for (int i=0;i<4;i++){
      float nm = fmaxf(mreg[i], pm[i]);
      sf[i] = __expf(mreg[i] - nm);
      mreg[i] = nm; psum[i] = 0.f;
    }
    #pragma unroll
    for (int nf=0;nf<4;nf++)
      #pragma unroll
      for (int i=0;i<4;i++){
        float e = __expf(sv[nf][i] - mreg[i]);
        sv[nf][i] = e; psum[i] += e;
      }
    #pragma unroll
    for (int i=0;i<4;i++){
      #pragma unroll
      for (int d=1; d<16; d<<=1) psum[i] += __shfl_xor(psum[i], d);
      lsum[i] = lsum[i]*sf[i] + psum[i];
    }
    #pragma unroll
    for (int nf=0;nf<8;nf++)
      #pragma unroll
      for (int i=0;i<4;i++) o[nf][i] *= sf[i];

    // ---- P round-trip (per-wave LDS, no barrier needed) ----
    #pragma unroll
    for (int nf=0;nf<4;nf++)
      #pragma unroll
      for (int i=0;i<4;i++){
        int qi = g*4 + i, kv = nf*16 + lr;
        int idx = qi*64 + (kv ^ ((qi&7)<<3));
        u16 hb = f2b(sv[nf][i]);
        Ph[w][idx] = hb;
        Pl[w][idx] = f2b(sv[nf][i] - b2f(hb));
      }

    // ---- PV (3-pass split) from LDS ----
    #pragma unroll
    for (int kk2=0; kk2<2; kk2++){
      int pidx = lr*64 + ((kk2*32 + g*8) ^ ((lr&7)<<3));
      bf16x8 ph = *(const bf16x8*)(&Ph[w][pidx]);
      bf16x8 pl = *(const bf16x8*)(&Pl[w][pidx]);
      __builtin_amdgcn_s_setprio(1);
      #pragma unroll
      for (int nf=0; nf<8; nf++){
        int row = nf*16 + lr;
        int off = row*64 + ((((kk2<<2)+g) ^ (lr&7))<<3);
        bf16x8 vf = *(const bf16x8*)(&KV[cur][2][off]);
        bf16x8 vg = *(const bf16x8*)(&KV[cur][3][off]);
        o[nf] = __builtin_amdgcn_mfma_f32_16x16x32_bf16(ph, vf, o[nf],0,0,0);
        o[nf] = __builtin_amdgcn_mfma_f32_16x16x32_bf16(ph, vg, o[nf],0,0,0);
        o[nf] = __builtin_amdgcn_mfma_f32_16x16x32_bf16(pl, vf, o[nf],0,0,0);
      }
      __builtin_amdgcn_s_setprio(0);
    }
    __builtin_amdgcn_s_barrier();   // all waves done with buf[cur] before overwrite
  }

  float inv[4];
  #pragma unroll
  for (int i=0;i<4;i++) inv[i] = 1.0f / lsum[i];
  #pragma unroll
  for (int nf=0;nf<8;nf++)
    #pragma unroll
    for (int i=0;i<4;i++){
      float v = o[nf][i] * inv[i];
      size_t oidx = (size_t)(q0 + g*4 + i)*2048 + head*HD + nf*16 + lr;
      u16 hb = f2b(v);
      oh_[oidx] = hb; ol_[oidx] = f2b(v - b2f(hb));
    }
}

// ---------------- router: fp32 logits, top-2, renorm ----------------
__global__ __launch_bounds__(256) void mx_router(
    const float* __restrict__ h2, const float* __restrict__ gw,
    int* __restrict__ meta, int* __restrict__ tki, float* __restrict__ tkw)
{
  int t = blockIdx.x, tid = threadIdx.x;
  float p[8] = {0,0,0,0,0,0,0,0};
  const float* row = h2 + (size_t)t*H_;
  for (int i = tid; i < H_; i += 256) {
    float x = row[i];
    #pragma unroll
    for (int e=0;e<8;e++) p[e] += x * gw[e*H_ + i];
  }
  #pragma unroll
  for (int e=0;e<8;e++)
    #pragma unroll
    for (int d=32; d; d>>=1) p[e] += __shfl_down(p[e], d);
  __shared__ float red[4][8];
  int w = tid>>6;
  if ((tid&63)==0){
    #pragma unroll
    for (int e=0;e<8;e++) red[w][e] = p[e];
  }
  __syncthreads();
  if (tid==0){
    float lg[8];
    #pragma unroll
    for (int e=0;e<8;e++) lg[e] = red[0][e]+red[1][e]+red[2][e]+red[3][e];
    int e0 = 0;
    for (int e=1;e<8;e++) if (lg[e] > lg[e0]) e0 = e;
    int e1 = (e0==0)?1:0;
    for (int e=0;e<8;e++) if (e!=e0 && lg[e] > lg[e1]) e1 = e;
    float w0 = 1.f/(1.f + __expf(lg[e1]-lg[e0]));
    tki[t*2]=e0; tki[t*2+1]=e1; tkw[t*2]=w0; tkw[t*2+1]=1.f-w0;
    atomicAdd(&meta[e0],1); atomicAdd(&meta[e1],1);
  }
}

// meta: [0..7]=counts [8..15]=poff [16..23]=ptiles [24..31]=cursor; gsh = tile granularity shift
__global__ void mx_scan(int* __restrict__ meta, int* __restrict__ perm, int gsh)
{
  if (threadIdx.x == 0){
    int run = 0;
    for (int e=0;e<8;e++){
      meta[8+e] = run;
      int pt = (meta[e] + (1<<gsh) - 1) >> gsh;
      meta[16+e] = pt;
      run += pt << gsh;
      meta[24+e] = 0;
    }
  }
  for (int i = threadIdx.x; i < PROWS; i += 256) perm[i] = 0;
}

__global__ void mx_scatter(const int* __restrict__ tki, int* __restrict__ meta,
                           int* __restrict__ perm, int* __restrict__ slot)
{
  int t = blockIdx.x*256 + threadIdx.x;
  if (t >= T_) return;
  #pragma unroll
  for (int j=0;j<2;j++){
    int e = tki[t*2+j];
    int s = atomicAdd(&meta[24+e], 1);
    int pos = meta[8+e] + s;
    perm[pos] = t;
    slot[t*2+j] = pos;
  }
}

__global__ void mx_combine(const float* __restrict__ Y2, const int* __restrict__ slot,
                           const float* __restrict__ tkw, float* __restrict__ out)
{
  int t = blockIdx.x, tid = threadIdx.x;
  int s0 = slot[t*2], s1 = slot[t*2+1];
  float w0 = tkw[t*2], w1 = tkw[t*2+1];
  const float4* r0 = (const float4*)(Y2 + (size_t)s0*H_);
  const float4* r1 = (const float4*)(Y2 + (size_t)s1*H_);
  float4* o4 = (float4*)(out + (size_t)t*H_);
  for (int i = tid; i < 512; i += 256){
    float4 a = r0[i], b = r1[i], c;
    c.x = w0*a.x + w1*b.x; c.y = w0*a.y + w1*b.y;
    c.z = w0*a.z + w1*b.z; c.w = w0*a.w + w1*b.w;
    o4[i] = c;
  }
}

extern "C" void kernel_launch(void* const* d_in, const int* in_sizes, int n_in,
                              void* d_out, int out_size, void* d_ws, size_t ws_size,
                              hipStream_t stream)
{
  (void)in_sizes; (void)n_in; (void)out_size;
  const int*   positions = (const int*)  d_in[0];
  const float* hidden    = (const float*)d_in[1];
  const float* residual  = (const float*)d_in[2];
  const float* ln1       = (const float*)d_in[3];
  const float* ln2       = (const float*)d_in[4];
  const float* wq        = (const float*)d_in[5];
  const float* wk        = (const float*)d_in[6];
  const float* wv        = (const float*)d_in[7];
  const float* wo        = (const float*)d_in[8];
  const float* gatew     = (const float*)d_in[9];
  const float* w1        = (const float*)d_in[10];
  const float* w3        = (const float*)d_in[11];
  const float* w2        = (const float*)d_in[12];
  float* outp = (float*)d_out;                 // [T*H] moe out, then [T*H] residual
  char* ws = (char*)d_ws;

  size_t off = 0;
  auto alloc = [&](size_t n){ size_t o = off; off += (n + 255) & ~(size_t)255; return o; };
  float* cosT = (float*)(ws + alloc((size_t)T_*64*4));
  float* sinT = (float*)(ws + alloc((size_t)T_*64*4));
  size_t res1_off = alloc((size_t)T_*H_*4);
  float* res1 = (float*)(ws + res1_off);
  u16*   h1h  = (u16*)  (ws + alloc((size_t)T_*H_*2));
  u16*   h1l  = (u16*)  (ws + alloc((size_t)T_*H_*2));
  float* qkvF = (float*)(ws + alloc((size_t)T_*3072*4));
  size_t qh_off = alloc((size_t)NH*T_*HD*2);
  u16*   qh   = (u16*)  (ws + qh_off);
  u16*   ql   = (u16*)  (ws + alloc((size_t)NH*T_*HD*2));
  u16*   kh   = (u16*)  (ws + alloc((size_t)NKV*T_*HD*2));
  u16*   kl   = (u16*)  (ws + alloc((size_t)NKV*T_*HD*2));
  u16*   vh   = (u16*)  (ws + alloc((size_t)NKV*T_*HD*2));
  u16*   vl   = (u16*)  (ws + alloc((size_t)NKV*T_*HD*2));
  u16*   aoh  = (u16*)  (ws + alloc((size_t)T_*2048*2));
  u16*   aol  = (u16*)  (ws + alloc((size_t)T_*2048*2));
  float* oF   = (float*)(ws + alloc((size_t)T_*H_*4));
  float* h2f  = (float*)(ws + alloc((size_t)T_*H_*4));
  u16*   h2b  = (u16*)  (ws + alloc((size_t)T_*H_*2));
  int*   meta = (int*)  (ws + alloc(32*4));
  int*   tki  = (int*)  (ws + alloc((size_t)T_*2*4));
  float* tkw  = (float*)(ws + alloc((size_t)T_*2*4));
  int*   slot = (int*)  (ws + alloc((size_t)T_*2*4));
  int*   perm = (int*)  (ws + alloc((size_t)PROWS*4));
  u16*   Y1   = (u16*)  (ws + alloc((size_t)PROWS*II_*2));
  // Y2 aliases qh..oF (dead before the w2 GEMM)
  float* Y2   = (float*)(ws + qh_off);
  u16* w1b = (u16*)(ws + alloc((size_t)NE*II_*H_*2));
  u16* w3b = (u16*)(ws + alloc((size_t)NE*II_*H_*2));
  u16* w2b = (u16*)(ws + alloc((size_t)NE*H_*II_*2));
  u16* qwh = (u16*)(ws + alloc((size_t)3072*H_*2));   // wq|wk|wv rows concat, split-hi
  u16* qwl = (u16*)(ws + alloc((size_t)3072*H_*2));
  u16* woh = (u16*)(ws + alloc((size_t)H_*H_*2));
  u16* wol = (u16*)(ws + alloc((size_t)H_*H_*2));

  // 0. small split conversions (attention-path weights)
  mx_cvt_split<<<512, 256, 0, stream>>>(wq, qwh,             qwl,             2048*2048/8);
  mx_cvt_split<<<512, 256, 0, stream>>>(wk, qwh + 2048*2048, qwl + 2048*2048, 512*2048/8);
  mx_cvt_split<<<512, 256, 0, stream>>>(wv, qwh + 2560*2048, qwl + 2560*2048, 512*2048/8);
  mx_cvt_split<<<512, 256, 0, stream>>>(wo, woh,             wol,             2048*2048/8);
  // 1. RoPE tables + fused add+norm1
  mx_rope_table<<<512, 256, 0, stream>>>(positions, cosT, sinT);
  mx_addnorm<<<T_, 256, 0, stream>>>(hidden, residual, ln1, res1, h1h, h1l,
                                     nullptr, nullptr, nullptr);
  // 2. QKV projection (3-pass split, fused single launch)
  mx_gemm3g<16,24><<<384, 256, 0, stream>>>(h1h, h1l, qwh, qwl, qkvF, 3072, H_);
  // 3. RoPE apply + V transpose
  mx_rope_apply<<<dim3(T_/4, NH+NKV), 256, 0, stream>>>(qkvF, cosT, sinT, qh, ql, kh, kl);
  mx_transpose_v<<<dim3(NKV, T_/64), 256, 0, stream>>>(qkvF, vh, vl);
  // 4. attention (y<8) + MoE weight conversion helpers (y>=8, 3840 blocks)
  mx_attn<<<dim3(T_/64, 128), 512, 0, stream>>>(qh, ql, kh, kl, vh, vl, aoh, aol,
                                                w1, w3, w2, w1b, w3b, w2b);
  // 5. o_proj (3-pass split)
  mx_gemm3g<16,16><<<256, 256, 0, stream>>>(aoh, aol, woh, wol, oF, 2048, 2048);
  // 6. add + norm2 (residual output + h2 fp32 + h2 bf16); zero expert counts
  mx_addnorm<<<T_, 256, 0, stream>>>(oF, res1, ln2, outp + (size_t)T_*H_,
                                     nullptr, nullptr, h2f, h2b, meta);
  // 7. router + routing metadata (256-granular tiles)
  mx_router<<<T_, 256, 0, stream>>>(h2f, gatew, meta, tki, tkw);
  mx_scan<<<1, 256, 0, stream>>>(meta, perm, 8);
  mx_scatter<<<T_/256, 256, 0, stream>>>(tki, meta, perm, slot);
  // 8. MoE expert GEMMs (w13: BM=256/8 waves; w2k: 128^2 with count-derived tiles)
  mx_moe_w13<32><<<2048, 512, 0, stream>>>(h2b, w1b, w3b, Y1, perm, meta);
  mx_moe_w2k<16><<<2048, 256, 0, stream>>>(Y1, w2b, Y2, meta);
  // 9. combine weighted expert outputs -> out
  mx_combine<<<T_, 256, 0, stream>>>(Y2, slot, tkw, outp);
  (void)ws_size;
}

// Round 14
// 1004.345 us; speedup vs baseline: 1.0814x; 1.0814x over previous
//
#include <hip/hip_runtime.h>
#include <hip/hip_bf16.h>
#include <math.h>

// Mixtral decoder layer, MI355X. T=2048 H=2048 NH=16 NKV=4 HD=128 I=4096 E=8 TOPK=2.
// Pre-router path (QKV, attn, o_proj): 3-pass bf16-split MFMA (~fp32 accurate) so the
// router top-k matches the fp32 reference; MoE expert path is plain bf16.
// R14: R12 configuration (best) + bf16 Y2 (w2k writes bf16, combine reads bf16).

#define T_  2048
#define H_  2048
#define NH  16
#define NKV 4
#define HD  128
#define II_ 4096
#define NE  8
#define EPS 1e-5f
#define PROWS 6144   // padded permuted rows

typedef __bf16 bf16x8 __attribute__((ext_vector_type(8)));
typedef float  f32x4  __attribute__((ext_vector_type(4)));
typedef unsigned short u16;

__device__ __forceinline__ u16 f2b(float f){ __bf16 b = (__bf16)f; return __builtin_bit_cast(u16, b); }
__device__ __forceinline__ float b2f(u16 u){ return (float)__builtin_bit_cast(__bf16, u); }

__device__ __forceinline__ void gll16(const void* g, void* l){
  __builtin_amdgcn_global_load_lds(
      (const __attribute__((address_space(1))) unsigned int*)g,
      (__attribute__((address_space(3))) unsigned int*)l, 16, 0, 0);
}

// ---------------- fp32 -> split (hi, lo) bf16 conversion ----------------
__global__ __launch_bounds__(256) void mx_cvt_split(const float* __restrict__ s,
                                                    u16* __restrict__ hi,
                                                    u16* __restrict__ lo, int n8)
{
  int i = blockIdx.x*256 + threadIdx.x;
  int stride = gridDim.x*256;
  for (; i < n8; i += stride){
    const f32x4* p = (const f32x4*)s + 2*(size_t)i;
    f32x4 a = p[0], b = p[1];
    uint4 uh, ul;
    u16 h0,h1,h2,h3;
    h0=f2b(a[0]); h1=f2b(a[1]); h2=f2b(a[2]); h3=f2b(a[3]);
    uh.x = (unsigned)h0 | ((unsigned)h1<<16);
    uh.y = (unsigned)h2 | ((unsigned)h3<<16);
    ul.x = (unsigned)f2b(a[0]-b2f(h0)) | ((unsigned)f2b(a[1]-b2f(h1))<<16);
    ul.y = (unsigned)f2b(a[2]-b2f(h2)) | ((unsigned)f2b(a[3]-b2f(h3))<<16);
    h0=f2b(b[0]); h1=f2b(b[1]); h2=f2b(b[2]); h3=f2b(b[3]);
    uh.z = (unsigned)h0 | ((unsigned)h1<<16);
    uh.w = (unsigned)h2 | ((unsigned)h3<<16);
    ul.z = (unsigned)f2b(b[0]-b2f(h0)) | ((unsigned)f2b(b[1]-b2f(h1))<<16);
    ul.w = (unsigned)f2b(b[2]-b2f(h2)) | ((unsigned)f2b(b[3]-b2f(h3))<<16);
    ((uint4*)hi)[i] = uh;
    ((uint4*)lo)[i] = ul;
  }
}

// ---------------- RoPE cos/sin table (double-precision inv_freq) ----------------
__global__ void mx_rope_table(const int* __restrict__ pos, float* __restrict__ cosT,
                              float* __restrict__ sinT)
{
  int i = blockIdx.x*256 + threadIdx.x;            // T*64
  int t = i >> 6, d = i & 63;
  float inv = (float)exp(-((double)d/64.0) * 9.210340371976184); // 10000^{-d/64}
  float f = (float)pos[t] * inv;
  cosT[i] = cosf(f); sinT[i] = sinf(f);
}

// ---------------- fused add + RMSNorm (writes several output forms) ----------------
__global__ __launch_bounds__(256) void mx_addnorm(
    const float* __restrict__ a, const float* __restrict__ b,
    const float* __restrict__ gam, float* __restrict__ res_out,
    u16* __restrict__ hi, u16* __restrict__ lo,
    float* __restrict__ hf, u16* __restrict__ hbf, int* __restrict__ mz)
{
  int t = blockIdx.x, tid = threadIdx.x;
  if (mz && t == 0 && tid < 8) mz[tid] = 0;
  const float4* A4 = (const float4*)a + (size_t)t*512;
  const float4* B4 = (const float4*)b + (size_t)t*512;
  float4 va = A4[tid], vb = B4[tid];
  float4 x0; x0.x=va.x+vb.x; x0.y=va.y+vb.y; x0.z=va.z+vb.z; x0.w=va.w+vb.w;
  va = A4[tid+256]; vb = B4[tid+256];
  float4 x1; x1.x=va.x+vb.x; x1.y=va.y+vb.y; x1.z=va.z+vb.z; x1.w=va.w+vb.w;
  float ss = x0.x*x0.x + x0.y*x0.y + x0.z*x0.z + x0.w*x0.w
           + x1.x*x1.x + x1.y*x1.y + x1.z*x1.z + x1.w*x1.w;
  #pragma unroll
  for (int d=32; d; d>>=1) ss += __shfl_down(ss, d);
  __shared__ float red[4];
  if ((tid&63)==0) red[tid>>6] = ss;
  __syncthreads();
  ss = red[0]+red[1]+red[2]+red[3];
  float scale = rsqrtf(ss * (1.f/2048.f) + EPS);
  float4* R4 = (float4*)res_out + (size_t)t*512;
  R4[tid] = x0; R4[tid+256] = x1;
  const float4* G4p = (const float4*)gam;
  float4 g0 = G4p[tid], g1 = G4p[tid+256];
  float4 y0; y0.x=x0.x*scale*g0.x; y0.y=x0.y*scale*g0.y; y0.z=x0.z*scale*g0.z; y0.w=x0.w*scale*g0.w;
  float4 y1; y1.x=x1.x*scale*g1.x; y1.y=x1.y*scale*g1.y; y1.z=x1.z*scale*g1.z; y1.w=x1.w*scale*g1.w;
  if (hf){ float4* H4 = (float4*)hf + (size_t)t*512; H4[tid]=y0; H4[tid+256]=y1; }
  if (hi){
    ushort4 uh, ul;
    uh.x=f2b(y0.x); ul.x=f2b(y0.x-b2f(uh.x));
    uh.y=f2b(y0.y); ul.y=f2b(y0.y-b2f(uh.y));
    uh.z=f2b(y0.z); ul.z=f2b(y0.z-b2f(uh.z));
    uh.w=f2b(y0.w); ul.w=f2b(y0.w-b2f(uh.w));
    ((ushort4*)hi)[(size_t)t*512 + tid] = uh; ((ushort4*)lo)[(size_t)t*512 + tid] = ul;
    uh.x=f2b(y1.x); ul.x=f2b(y1.x-b2f(uh.x));
    uh.y=f2b(y1.y); ul.y=f2b(y1.y-b2f(uh.y));
    uh.z=f2b(y1.z); ul.z=f2b(y1.z-b2f(uh.z));
    uh.w=f2b(y1.w); ul.w=f2b(y1.w-b2f(uh.w));
    ((ushort4*)hi)[(size_t)t*512 + tid+256] = uh; ((ushort4*)lo)[(size_t)t*512 + tid+256] = ul;
  }
  if (hbf){
    ushort4 u0; u0.x=f2b(y0.x); u0.y=f2b(y0.y); u0.z=f2b(y0.z); u0.w=f2b(y0.w);
    ushort4 u1; u1.x=f2b(y1.x); u1.y=f2b(y1.y); u1.z=f2b(y1.z); u1.w=f2b(y1.w);
    ((ushort4*)hbf)[(size_t)t*512 + tid] = u0; ((ushort4*)hbf)[(size_t)t*512 + tid+256] = u1;
  }
}

// ------- 3-pass split GEMM, gll16 m97 skeleton: C = A(hi,lo) x B(hi,lo)^T, fp32 out -------
template<int NX, int NY>
__global__ __launch_bounds__(256,2) void mx_gemm3g(
    const u16* __restrict__ Ah, const u16* __restrict__ Al,
    const u16* __restrict__ Bh, const u16* __restrict__ Bl,
    float* __restrict__ C, int ldc, int K)
{
  __shared__ u16 AhS[128*64], AlS[128*64], BhS[128*64], BlS[128*64];
  int bid = blockIdx.x;
  int xcd = bid & 7, j = bid >> 3;
  int x = j % NX, p = j / NX;
  int y = xcd + 8*p;
  int m0 = x*128, n0 = y*128;
  int tid = threadIdx.x;
  int w = tid>>6, lane = tid&63, wr = w>>1, wc = w&1, g = lane>>4, lr = lane&15;
  f32x4 acc[4][4];
  #pragma unroll
  for (int fm=0;fm<4;fm++)
    #pragma unroll
    for (int fn=0;fn<4;fn++) acc[fm][fn] = (f32x4){0.f,0.f,0.f,0.f};

  for (int k0 = 0; k0 < K; k0 += 64) {
    #pragma unroll
    for (int i=0;i<4;i++){
      int c = i*256 + tid, r = c>>3, ch = c&7;
      int sw = ((ch ^ (r&7))<<3);
      int db = (i*256 + w*64)<<3;
      gll16(Ah + (size_t)(m0+r)*K + k0 + sw, &AhS[db]);
      gll16(Al + (size_t)(m0+r)*K + k0 + sw, &AlS[db]);
      gll16(Bh + (size_t)(n0+r)*K + k0 + sw, &BhS[db]);
      gll16(Bl + (size_t)(n0+r)*K + k0 + sw, &BlS[db]);
    }
    __syncthreads();
    #pragma unroll
    for (int kk=0;kk<2;kk++){
      bf16x8 ah[4], al[4], bh[4], bl[4];
      #pragma unroll
      for (int fm=0;fm<4;fm++){
        int r = wr*64 + fm*16 + lr;
        int ch = ((kk<<2)+g) ^ (r&7);
        ah[fm] = *(const bf16x8*)(&AhS[(r<<6)+(ch<<3)]);
        al[fm] = *(const bf16x8*)(&AlS[(r<<6)+(ch<<3)]);
      }
      #pragma unroll
      for (int fn=0;fn<4;fn++){
        int r = wc*64 + fn*16 + lr;
        int ch = ((kk<<2)+g) ^ (r&7);
        bh[fn] = *(const bf16x8*)(&BhS[(r<<6)+(ch<<3)]);
        bl[fn] = *(const bf16x8*)(&BlS[(r<<6)+(ch<<3)]);
      }
      __builtin_amdgcn_s_setprio(1);
      #pragma unroll
      for (int fm=0;fm<4;fm++)
        #pragma unroll
        for (int fn=0;fn<4;fn++){
          acc[fm][fn] = __builtin_amdgcn_mfma_f32_16x16x32_bf16(ah[fm], bh[fn], acc[fm][fn],0,0,0);
          acc[fm][fn] = __builtin_amdgcn_mfma_f32_16x16x32_bf16(ah[fm], bl[fn], acc[fm][fn],0,0,0);
          acc[fm][fn] = __builtin_amdgcn_mfma_f32_16x16x32_bf16(al[fm], bh[fn], acc[fm][fn],0,0,0);
        }
      __builtin_amdgcn_s_setprio(0);
    }
    __syncthreads();
  }
  #pragma unroll
  for (int fm=0;fm<4;fm++)
    #pragma unroll
    for (int fn=0;fn<4;fn++)
      #pragma unroll
      for (int i=0;i<4;i++){
        size_t rg = (size_t)(m0 + wr*64 + fm*16 + g*4 + i);
        int cg = n0 + wc*64 + fn*16 + lr;
        C[rg*ldc + cg] = acc[fm][fn][i];
      }
}

// ------------- MoE w1+w3 fused GEMM + silu epilogue (all-bf16, m97-style) -------------
template<int NY>
__global__ __launch_bounds__(256,2) void mx_moe_w13(
    const u16* __restrict__ A,
    const u16* __restrict__ B1, const u16* __restrict__ B3,
    u16* __restrict__ Y,
    const int* __restrict__ row_map, const int* __restrict__ meta)
{
  __shared__ u16 As[128*64], B1s[128*64], B3s[128*64];
  int bid = blockIdx.x;
  int xcd = bid & 7, j = bid >> 3;
  int x = j & 15, p = j >> 4;
  int panel = xcd + 8*p;                 // < NE*NY
  int e = panel / NY, y = panel % NY;
  if (x >= meta[16+e]) return;
  int rowbase = meta[8+e] + (x<<7);
  const u16* B1p = B1 + ((size_t)e*II_ + y*128)*H_;
  const u16* B3p = B3 + ((size_t)e*II_ + y*128)*H_;
  int tid = threadIdx.x;
  int w = tid>>6, lane = tid&63, wr = w>>1, wc = w&1, g = lane>>4, lr = lane&15;

  f32x4 acc1[4][4], acc3[4][4];
  #pragma unroll
  for (int fm=0;fm<4;fm++)
    #pragma unroll
    for (int fn=0;fn<4;fn++){ acc1[fm][fn]=(f32x4){0,0,0,0}; acc3[fm][fn]=(f32x4){0,0,0,0}; }

  for (int k0 = 0; k0 < H_; k0 += 64) {
    #pragma unroll
    for (int i=0;i<4;i++){
      int c = i*256 + tid, r = c>>3, ch = c&7;
      int sw = (ch ^ (r&7))<<3;
      int db = (i*256 + w*64)<<3;
      int grow = row_map[rowbase + r];
      gll16(A   + (size_t)grow*H_ + k0 + sw, &As[db]);
      gll16(B1p + (size_t)r*H_    + k0 + sw, &B1s[db]);
      gll16(B3p + (size_t)r*H_    + k0 + sw, &B3s[db]);
    }
    __syncthreads();
    #pragma unroll
    for (int kk=0;kk<2;kk++){
      bf16x8 af[4], b1f[4], b3f[4];
      #pragma unroll
      for (int fm=0;fm<4;fm++){
        int r = wr*64 + fm*16 + lr;
        int ch = ((kk<<2)+g) ^ (r&7);
        af[fm] = *(const bf16x8*)(&As[(r<<6)+(ch<<3)]);
      }
      #pragma unroll
      for (int fn=0;fn<4;fn++){
        int r = wc*64 + fn*16 + lr;
        int ch = ((kk<<2)+g) ^ (r&7);
        b1f[fn] = *(const bf16x8*)(&B1s[(r<<6)+(ch<<3)]);
        b3f[fn] = *(const bf16x8*)(&B3s[(r<<6)+(ch<<3)]);
      }
      __builtin_amdgcn_s_setprio(1);
      #pragma unroll
      for (int fm=0;fm<4;fm++)
        #pragma unroll
        for (int fn=0;fn<4;fn++){
          acc1[fm][fn] = __builtin_amdgcn_mfma_f32_16x16x32_bf16(af[fm], b1f[fn], acc1[fm][fn],0,0,0);
          acc3[fm][fn] = __builtin_amdgcn_mfma_f32_16x16x32_bf16(af[fm], b3f[fn], acc3[fm][fn],0,0,0);
        }
      __builtin_amdgcn_s_setprio(0);
    }
    __syncthreads();
  }
  int n0 = y*128 + wc*64;
  #pragma unroll
  for (int fm=0;fm<4;fm++)
    #pragma unroll
    for (int fn=0;fn<4;fn++)
      #pragma unroll
      for (int i=0;i<4;i++){
        size_t rg = (size_t)(rowbase + wr*64 + fm*16 + g*4 + i);
        int cg = n0 + fn*16 + lr;
        float gg = acc1[fm][fn][i], uu = acc3[fm][fn][i];
        float sg = gg / (1.f + __expf(-gg));
        Y[rg*II_ + cg] = f2b(sg * uu);
      }
}

// ------------- MoE w2 GEMM (all-bf16, m97-style): Y2(bf16) = Y . w2^T -------------
template<int NY>
__global__ __launch_bounds__(256,2) void mx_moe_w2k(
    const u16* __restrict__ A,       // Y bf16 [PROWS][II_]
    const u16* __restrict__ B,       // w2b bf16 [E][H_][II_]
    u16* __restrict__ C,             // Y2 bf16 [PROWS][H_]
    const int* __restrict__ meta)
{
  __shared__ u16 As[128*64], Bs[128*64];
  int bid = blockIdx.x;
  int xcd = bid & 7, j = bid >> 3;
  int x = j & 15, p = j >> 4;
  int panel = xcd + 8*p;                 // < NE*NY
  int e = panel / NY, y = panel % NY;
  if (x >= meta[16+e]) return;
  int rowbase = meta[8+e] + (x<<7);
  const u16* Bp = B + ((size_t)e*H_ + y*128)*II_;
  int tid = threadIdx.x;
  int w = tid>>6, lane = tid&63, wr = w>>1, wc = w&1, g = lane>>4, lr = lane&15;

  f32x4 acc[4][4];
  #pragma unroll
  for (int fm=0;fm<4;fm++)
    #pragma unroll
    for (int fn=0;fn<4;fn++) acc[fm][fn] = (f32x4){0,0,0,0};

  for (int k0 = 0; k0 < II_; k0 += 64) {
    #pragma unroll
    for (int i=0;i<4;i++){
      int c = i*256 + tid, r = c>>3, ch = c&7;
      int sw = (ch ^ (r&7))<<3;
      int db = (i*256 + w*64)<<3;
      gll16(A  + (size_t)(rowbase + r)*II_ + k0 + sw, &As[db]);
      gll16(Bp + (size_t)r*II_             + k0 + sw, &Bs[db]);
    }
    __syncthreads();
    #pragma unroll
    for (int kk=0;kk<2;kk++){
      bf16x8 af[4], bf[4];
      #pragma unroll
      for (int fm=0;fm<4;fm++){
        int r = wr*64 + fm*16 + lr;
        int ch = ((kk<<2)+g) ^ (r&7);
        af[fm] = *(const bf16x8*)(&As[(r<<6)+(ch<<3)]);
      }
      #pragma unroll
      for (int fn=0;fn<4;fn++){
        int r = wc*64 + fn*16 + lr;
        int ch = ((kk<<2)+g) ^ (r&7);
        bf[fn] = *(const bf16x8*)(&Bs[(r<<6)+(ch<<3)]);
      }
      __builtin_amdgcn_s_setprio(1);
      #pragma unroll
      for (int fm=0;fm<4;fm++)
        #pragma unroll
        for (int fn=0;fn<4;fn++)
          acc[fm][fn] = __builtin_amdgcn_mfma_f32_16x16x32_bf16(af[fm], bf[fn], acc[fm][fn],0,0,0);
      __builtin_amdgcn_s_setprio(0);
    }
    __syncthreads();
  }
  int n0 = y*128 + wc*64;
  #pragma unroll
  for (int fm=0;fm<4;fm++)
    #pragma unroll
    for (int fn=0;fn<4;fn++)
      #pragma unroll
      for (int i=0;i<4;i++){
        size_t rg = (size_t)(rowbase + wr*64 + fm*16 + g*4 + i);
        int cg = n0 + fn*16 + lr;
        C[rg*H_ + cg] = f2b(acc[fm][fn][i]);
      }
}

// ---------------- RoPE apply: qkv fp32 -> split-bf16 Q [h][t][d], K [kv][t][d] ----------------
__global__ __launch_bounds__(256) void mx_rope_apply(const float* __restrict__ qkv,
    const float* __restrict__ cosT, const float* __restrict__ sinT,
    u16* __restrict__ qh, u16* __restrict__ ql, u16* __restrict__ kh, u16* __restrict__ kl)
{
  int t = blockIdx.x*4 + (threadIdx.x>>6);
  int hh = blockIdx.y, d = threadIdx.x & 63;
  const float* row = qkv + (size_t)t*3072;
  float c = cosT[t*64+d], s = sinT[t*64+d];
  float x1, x2; size_t base; u16 *oh, *ol;
  if (hh < NH){ x1 = row[hh*HD+d]; x2 = row[hh*HD+d+64];
     base = ((size_t)hh*T_ + t)*HD; oh = qh; ol = ql; }
  else { int kvh = hh-NH; x1 = row[2048 + kvh*HD + d]; x2 = row[2048 + kvh*HD + d + 64];
     base = ((size_t)kvh*T_ + t)*HD; oh = kh; ol = kl; }
  float o1 = x1*c - x2*s, o2 = x2*c + x1*s;
  u16 a = f2b(o1); oh[base+d]    = a; ol[base+d]    = f2b(o1 - b2f(a));
  u16 b = f2b(o2); oh[base+d+64] = b; ol[base+d+64] = f2b(o2 - b2f(b));
}

// ---------------- V transpose: qkv fp32 -> split-bf16 V^T [kv][d][t] ----------------
__global__ void mx_transpose_v(const float* __restrict__ qkv,
                               u16* __restrict__ vh, u16* __restrict__ vl)
{
  __shared__ float tile[64][132];
  int kv = blockIdx.x, t0 = blockIdx.y*64, tid = threadIdx.x;
  #pragma unroll
  for (int it=0; it<32; ++it){
    int idx = it*256 + tid; int r = idx>>7, d = idx&127;
    tile[r][d] = qkv[(size_t)(t0+r)*3072 + 2560 + kv*HD + d];
  }
  __syncthreads();
  #pragma unroll
  for (int it=0; it<32; ++it){
    int idx = it*256 + tid; int d = idx>>6, j = idx&63;
    float x = tile[j][d];
    u16 a = f2b(x);
    size_t o = ((size_t)kv*HD + d)*T_ + t0 + j;
    vh[o] = a; vl[o] = f2b(x - b2f(a));
  }
}

// ---------------- flash attention (y<8) + weight-cvt helper blocks (y>=8) ----------------
// Attention: 2 heads/block, 8 waves, dbuf 160KB LDS, counted vmcnt(8) (R11-proven).
// Helpers: grid-stride fp32->bf16 conversion of w1/w3/w2 — backfill CUs idled by
// causal imbalance (attn blocks dispatch first: lower linear IDs).
__global__ __launch_bounds__(512) void mx_attn(
  const u16* __restrict__ qh_, const u16* __restrict__ ql_,
  const u16* __restrict__ kh_, const u16* __restrict__ kl_,
  const u16* __restrict__ vh_, const u16* __restrict__ vl_,
  u16* __restrict__ oh_, u16* __restrict__ ol_,
  const float* __restrict__ w1f, const float* __restrict__ w3f,
  const float* __restrict__ w2f,
  u16* __restrict__ w1b, u16* __restrict__ w3b, u16* __restrict__ w2b)
{
  if (blockIdx.y >= 8){
    // -------- cvt helper path (no LDS, no barriers) --------
    const int n8 = NE*II_*H_/8;                       // 8388608 per matrix
    int hb = (blockIdx.y - 8)*gridDim.x + blockIdx.x; // 0..3839
    int i  = hb*512 + threadIdx.x;
    const int stride = 3840*512;
    for (; i < 3*n8; i += stride){
      const float* s; u16* d; int j;
      if (i < n8)        { s = w1f; d = w1b; j = i; }
      else if (i < 2*n8) { s = w3f; d = w3b; j = i - n8; }
      else               { s = w2f; d = w2b; j = i - 2*n8; }
      const f32x4* p = (const f32x4*)s + 2*(size_t)j;
      f32x4 a = p[0], b = p[1];
      uint4 u;
      u.x = (unsigned)f2b(a[0]) | ((unsigned)f2b(a[1])<<16);
      u.y = (unsigned)f2b(a[2]) | ((unsigned)f2b(a[3])<<16);
      u.z = (unsigned)f2b(b[0]) | ((unsigned)f2b(b[1])<<16);
      u.w = (unsigned)f2b(b[2]) | ((unsigned)f2b(b[3])<<16);
      ((uint4*)d)[j] = u;
    }
    return;
  }

  int pair = blockIdx.y;                    // 0..7 -> heads (2p, 2p+1)
  int kvh = pair >> 1;
  int qt = (pair & 4) ? (31 - (int)blockIdx.x) : (int)blockIdx.x;
  int tid = threadIdx.x, w = tid>>6, lane = tid&63, g = lane>>4, lr = lane&15;
  int head = pair*2 + (w>>2);
  int q0 = qt*64 + (w&3)*16;
  __shared__ u16 KV[2][4][8192];            // [buf][Kh,Kl,Vh,Vl] 128 KB
  __shared__ u16 Ph[8][1024], Pl[8][1024];  // 32 KB (per-wave)

  bf16x8 qfh[4], qfl[4];
  const u16* qrh = qh_ + ((size_t)head*T_ + q0 + lr)*HD;
  const u16* qrl = ql_ + ((size_t)head*T_ + q0 + lr)*HD;
  #pragma unroll
  for (int kk=0;kk<4;kk++){
    qfh[kk] = *(const bf16x8*)(qrh + kk*32 + g*8);
    qfl[kk] = *(const bf16x8*)(qrl + kk*32 + g*8);
  }
  f32x4 o[8];
  #pragma unroll
  for (int nf=0;nf<8;nf++) o[nf] = (f32x4){0.f,0.f,0.f,0.f};
  float mreg[4] = {-3e38f,-3e38f,-3e38f,-3e38f}, lsum[4] = {0.f,0.f,0.f,0.f};

  const u16* kbase = kh_ + (size_t)kvh*T_*HD;
  const u16* lbase = kl_ + (size_t)kvh*T_*HD;
  const u16* vbase = vh_ + (size_t)kvh*HD*T_;
  const u16* wbase = vl_ + (size_t)kvh*HD*T_;

  auto stage = [&](int buf, int kvb){
    #pragma unroll
    for (int i=0;i<2;i++){
      int cb = i*512 + w*64;                // wave-uniform chunk base (0..1023)
      int c  = cb + lane;
      int kr = c>>4, kc = ((c&15) ^ (kr&7))<<3;
      gll16(kbase + (size_t)(kvb+kr)*HD + kc, &KV[buf][0][cb*8]);
      gll16(lbase + (size_t)(kvb+kr)*HD + kc, &KV[buf][1][cb*8]);
      int vr = c>>3, vc = ((c&7) ^ (vr&7))<<3;
      gll16(vbase + (size_t)vr*T_ + kvb + vc, &KV[buf][2][cb*8]);
      gll16(wbase + (size_t)vr*T_ + kvb + vc, &KV[buf][3][cb*8]);
    }
  };

  stage(0, 0);      // prologue: 8 loads/thread in flight

  for (int kt = 0; kt <= qt; ++kt) {
    int cur = kt & 1;
    int kvb = kt*64;
    if (kt < qt) {
      stage(cur^1, kvb+64);
      asm volatile("s_waitcnt vmcnt(8)" ::: "memory");   // cur tile landed, next in flight
    } else {
      asm volatile("s_waitcnt vmcnt(0)" ::: "memory");
    }
    __builtin_amdgcn_s_barrier();

    // ---- QK^T (3-pass split) from LDS ----
    f32x4 s[4];
    #pragma unroll
    for (int nf=0;nf<4;nf++) s[nf] = (f32x4){0.f,0.f,0.f,0.f};
    __builtin_amdgcn_s_setprio(1);
    #pragma unroll
    for (int nf=0; nf<4; nf++){
      int row = nf*16 + lr;
      #pragma unroll
      for (int kk=0;kk<4;kk++){
        int off = row*128 + ((((kk<<2)+g) ^ (lr&7))<<3);
        bf16x8 kf = *(const bf16x8*)(&KV[cur][0][off]);
        bf16x8 kg = *(const bf16x8*)(&KV[cur][1][off]);
        s[nf] = __builtin_amdgcn_mfma_f32_16x16x32_bf16(qfh[kk], kf, s[nf],0,0,0);
        s[nf] = __builtin_amdgcn_mfma_f32_16x16x32_bf16(qfh[kk], kg, s[nf],0,0,0);
        s[nf] = __builtin_amdgcn_mfma_f32_16x16x32_bf16(qfl[kk], kf, s[nf],0,0,0);
      }
    }
    __builtin_amdgcn_s_setprio(0);

    // ---- online softmax ----
    float sv[4][4], pm[4];
    #pragma unroll
    for (int i=0;i<4;i++) pm[i] = -3e38f;
    bool diag = (kt == qt);
    #pragma unroll
    for (int nf=0;nf<4;nf++)
      #pragma unroll
      for (int i=0;i<4;i++){
        float v = s[nf][i] * 0.08838834764831845f;
        if (diag && (kvb + nf*16 + lr > q0 + g*4 + i)) v = -1e30f;
        sv[nf][i] = v;
        pm[i] = fmaxf(pm[i], v);
      }
    #pragma unroll
    for (int i=0;i<4;i++)
      #pragma unroll
      for (int d=1; d<16; d<<=1) pm[i] = fmaxf(pm[i], __shfl_xor(pm[i], d));
    float sf[4], psum[4];
    #pragma unroll
    for (int i=0;i<4;i++){
      float nm = fmaxf(mreg[i], pm[i]);
      sf[i] = __expf(mreg[i] - nm);
      mreg[i] = nm; psum[i] = 0.f;
    }
    #pragma unroll
    for (int nf=0;nf<4;nf++)
      #pragma unroll
      for (int i=0;i<4;i++){
        float e = __expf(sv[nf][i] - mreg[i]);
        sv[nf][i] = e; psum[i] += e;
      }
    #pragma unroll
    for (int i=0;i<4;i++){
      #pragma unroll
      for (int d=1; d<16; d<<=1) psum[i] += __shfl_xor(psum[i], d);
      lsum[i] = lsum[i]*sf[i] + psum[i];
    }
    #pragma unroll
    for (int nf=0;nf<8;nf++)
      #pragma unroll
      for (int i=0;i<4;i++) o[nf][i] *= sf[i];

    // ---- P round-trip (per-wave LDS, no barrier needed) ----
    #pragma unroll
    for (int nf=0;nf<4;nf++)
      #pragma unroll
      for (int i=0;i<4;i++){
        int qi = g*4 + i, kv = nf*16 + lr;
        int idx = qi*64 + (kv ^ ((qi&7)<<3));
        u16 hb = f2b(sv[nf][i]);
        Ph[w][idx] = hb;
        Pl[w][idx] = f2b(sv[nf][i] - b2f(hb));
      }

    // ---- PV (3-pass split) from LDS ----
    #pragma unroll
    for (int kk2=0; kk2<2; kk2++){
      int pidx = lr*64 + ((kk2*32 + g*8) ^ ((lr&7)<<3));
      bf16x8 ph = *(const bf16x8*)(&Ph[w][pidx]);
      bf16x8 pl = *(const bf16x8*)(&Pl[w][pidx]);
      __builtin_amdgcn_s_setprio(1);
      #pragma unroll
      for (int nf=0; nf<8; nf++){
        int row = nf*16 + lr;
        int off = row*64 + ((((kk2<<2)+g) ^ (lr&7))<<3);
        bf16x8 vf = *(const bf16x8*)(&KV[cur][2][off]);
        bf16x8 vg = *(const bf16x8*)(&KV[cur][3][off]);
        o[nf] = __builtin_amdgcn_mfma_f32_16x16x32_bf16(ph, vf, o[nf],0,0,0);
        o[nf] = __builtin_amdgcn_mfma_f32_16x16x32_bf16(ph, vg, o[nf],0,0,0);
        o[nf] = __builtin_amdgcn_mfma_f32_16x16x32_bf16(pl, vf, o[nf],0,0,0);
      }
      __builtin_amdgcn_s_setprio(0);
    }
    __builtin_amdgcn_s_barrier();   // all waves done with buf[cur] before overwrite
  }

  float inv[4];
  #pragma unroll
  for (int i=0;i<4;i++) inv[i] = 1.0f / lsum[i];
  #pragma unroll
  for (int nf=0;nf<8;nf++)
    #pragma unroll
    for (int i=0;i<4;i++){
      float v = o[nf][i] * inv[i];
      size_t oidx = (size_t)(q0 + g*4 + i)*2048 + head*HD + nf*16 + lr;
      u16 hb = f2b(v);
      oh_[oidx] = hb; ol_[oidx] = f2b(v - b2f(hb));
    }
}

// ---------------- router: fp32 logits, top-2, renorm ----------------
__global__ __launch_bounds__(256) void mx_router(
    const float* __restrict__ h2, const float* __restrict__ gw,
    int* __restrict__ meta, int* __restrict__ tki, float* __restrict__ tkw)
{
  int t = blockIdx.x, tid = threadIdx.x;
  float p[8] = {0,0,0,0,0,0,0,0};
  const float* row = h2 + (size_t)t*H_;
  for (int i = tid; i < H_; i += 256) {
    float x = row[i];
    #pragma unroll
    for (int e=0;e<8;e++) p[e] += x * gw[e*H_ + i];
  }
  #pragma unroll
  for (int e=0;e<8;e++)
    #pragma unroll
    for (int d=32; d; d>>=1) p[e] += __shfl_down(p[e], d);
  __shared__ float red[4][8];
  int w = tid>>6;
  if ((tid&63)==0){
    #pragma unroll
    for (int e=0;e<8;e++) red[w][e] = p[e];
  }
  __syncthreads();
  if (tid==0){
    float lg[8];
    #pragma unroll
    for (int e=0;e<8;e++) lg[e] = red[0][e]+red[1][e]+red[2][e]+red[3][e];
    int e0 = 0;
    for (int e=1;e<8;e++) if (lg[e] > lg[e0]) e0 = e;
    int e1 = (e0==0)?1:0;
    for (int e=0;e<8;e++) if (e!=e0 && lg[e] > lg[e1]) e1 = e;
    float w0 = 1.f/(1.f + __expf(lg[e1]-lg[e0]));
    tki[t*2]=e0; tki[t*2+1]=e1; tkw[t*2]=w0; tkw[t*2+1]=1.f-w0;
    atomicAdd(&meta[e0],1); atomicAdd(&meta[e1],1);
  }
}

// meta: [0..7]=counts [8..15]=poff [16..23]=ptiles [24..31]=cursor; gsh = tile granularity shift
__global__ void mx_scan(int* __restrict__ meta, int* __restrict__ perm, int gsh)
{
  if (threadIdx.x == 0){
    int run = 0;
    for (int e=0;e<8;e++){
      meta[8+e] = run;
      int pt = (meta[e] + (1<<gsh) - 1) >> gsh;
      meta[16+e] = pt;
      run += pt << gsh;
      meta[24+e] = 0;
    }
  }
  for (int i = threadIdx.x; i < PROWS; i += 256) perm[i] = 0;
}

__global__ void mx_scatter(const int* __restrict__ tki, int* __restrict__ meta,
                           int* __restrict__ perm, int* __restrict__ slot)
{
  int t = blockIdx.x*256 + threadIdx.x;
  if (t >= T_) return;
  #pragma unroll
  for (int j=0;j<2;j++){
    int e = tki[t*2+j];
    int s = atomicAdd(&meta[24+e], 1);
    int pos = meta[8+e] + s;
    perm[pos] = t;
    slot[t*2+j] = pos;
  }
}

__global__ void mx_combine(const u16* __restrict__ Y2, const int* __restrict__ slot,
                           const float* __restrict__ tkw, float* __restrict__ out)
{
  int t = blockIdx.x, tid = threadIdx.x;
  int s0 = slot[t*2], s1 = slot[t*2+1];
  float w0 = tkw[t*2], w1 = tkw[t*2+1];
  const uint4* r0 = (const uint4*)(Y2 + (size_t)s0*H_);
  const uint4* r1 = (const uint4*)(Y2 + (size_t)s1*H_);
  float4* o4 = (float4*)(out + (size_t)t*H_);
  for (int i = tid; i < 256; i += 256){
    uint4 a = r0[i], b = r1[i];
    const u16* ap = (const u16*)&a;
    const u16* bp = (const u16*)&b;
    float4 c0, c1;
    c0.x = w0*b2f(ap[0]) + w1*b2f(bp[0]);
    c0.y = w0*b2f(ap[1]) + w1*b2f(bp[1]);
    c0.z = w0*b2f(ap[2]) + w1*b2f(bp[2]);
    c0.w = w0*b2f(ap[3]) + w1*b2f(bp[3]);
    c1.x = w0*b2f(ap[4]) + w1*b2f(bp[4]);
    c1.y = w0*b2f(ap[5]) + w1*b2f(bp[5]);
    c1.z = w0*b2f(ap[6]) + w1*b2f(bp[6]);
    c1.w = w0*b2f(ap[7]) + w1*b2f(bp[7]);
    o4[i*2]   = c0;
    o4[i*2+1] = c1;
  }
}

extern "C" void kernel_launch(void* const* d_in, const int* in_sizes, int n_in,
                              void* d_out, int out_size, void* d_ws, size_t ws_size,
                              hipStream_t stream)
{
  (void)in_sizes; (void)n_in; (void)out_size;
  const int*   positions = (const int*)  d_in[0];
  const float* hidden    = (const float*)d_in[1];
  const float* residual  = (const float*)d_in[2];
  const float* ln1       = (const float*)d_in[3];
  const float* ln2       = (const float*)d_in[4];
  const float* wq        = (const float*)d_in[5];
  const float* wk        = (const float*)d_in[6];
  const float* wv        = (const float*)d_in[7];
  const float* wo        = (const float*)d_in[8];
  const float* gatew     = (const float*)d_in[9];
  const float* w1        = (const float*)d_in[10];
  const float* w3        = (const float*)d_in[11];
  const float* w2        = (const float*)d_in[12];
  float* outp = (float*)d_out;                 // [T*H] moe out, then [T*H] residual
  char* ws = (char*)d_ws;

  size_t off = 0;
  auto alloc = [&](size_t n){ size_t o = off; off += (n + 255) & ~(size_t)255; return o; };
  float* cosT = (float*)(ws + alloc((size_t)T_*64*4));
  float* sinT = (float*)(ws + alloc((size_t)T_*64*4));
  size_t res1_off = alloc((size_t)T_*H_*4);
  float* res1 = (float*)(ws + res1_off);
  u16*   h1h  = (u16*)  (ws + alloc((size_t)T_*H_*2));
  u16*   h1l  = (u16*)  (ws + alloc((size_t)T_*H_*2));
  float* qkvF = (float*)(ws + alloc((size_t)T_*3072*4));
  size_t qh_off = alloc((size_t)NH*T_*HD*2);
  u16*   qh   = (u16*)  (ws + qh_off);
  u16*   ql   = (u16*)  (ws + alloc((size_t)NH*T_*HD*2));
  u16*   kh   = (u16*)  (ws + alloc((size_t)NKV*T_*HD*2));
  u16*   kl   = (u16*)  (ws + alloc((size_t)NKV*T_*HD*2));
  u16*   vh   = (u16*)  (ws + alloc((size_t)NKV*T_*HD*2));
  u16*   vl   = (u16*)  (ws + alloc((size_t)NKV*T_*HD*2));
  u16*   aoh  = (u16*)  (ws + alloc((size_t)T_*2048*2));
  u16*   aol  = (u16*)  (ws + alloc((size_t)T_*2048*2));
  float* oF   = (float*)(ws + alloc((size_t)T_*H_*4));
  float* h2f  = (float*)(ws + alloc((size_t)T_*H_*4));
  u16*   h2b  = (u16*)  (ws + alloc((size_t)T_*H_*2));
  int*   meta = (int*)  (ws + alloc(32*4));
  int*   tki  = (int*)  (ws + alloc((size_t)T_*2*4));
  float* tkw  = (float*)(ws + alloc((size_t)T_*2*4));
  int*   slot = (int*)  (ws + alloc((size_t)T_*2*4));
  int*   perm = (int*)  (ws + alloc((size_t)PROWS*4));
  u16*   Y1   = (u16*)  (ws + alloc((size_t)PROWS*II_*2));
  // Y2 (bf16) aliases qh..oF region (dead before the w2 GEMM)
  u16*   Y2   = (u16*)(ws + qh_off);
  u16* w1b = (u16*)(ws + alloc((size_t)NE*II_*H_*2));
  u16* w3b = (u16*)(ws + alloc((size_t)NE*II_*H_*2));
  u16* w2b = (u16*)(ws + alloc((size_t)NE*H_*II_*2));
  u16* qwh = (u16*)(ws + alloc((size_t)3072*H_*2));   // wq|wk|wv rows concat, split-hi
  u16* qwl = (u16*)(ws + alloc((size_t)3072*H_*2));
  u16* woh = (u16*)(ws + alloc((size_t)H_*H_*2));
  u16* wol = (u16*)(ws + alloc((size_t)H_*H_*2));

  // 0. small split conversions (attention-path weights)
  mx_cvt_split<<<512, 256, 0, stream>>>(wq, qwh,             qwl,             2048*2048/8);
  mx_cvt_split<<<512, 256, 0, stream>>>(wk, qwh + 2048*2048, qwl + 2048*2048, 512*2048/8);
  mx_cvt_split<<<512, 256, 0, stream>>>(wv, qwh + 2560*2048, qwl + 2560*2048, 512*2048/8);
  mx_cvt_split<<<512, 256, 0, stream>>>(wo, woh,             wol,             2048*2048/8);
  // 1. RoPE tables + fused add+norm1
  mx_rope_table<<<512, 256, 0, stream>>>(positions, cosT, sinT);
  mx_addnorm<<<T_, 256, 0, stream>>>(hidden, residual, ln1, res1, h1h, h1l,
                                     nullptr, nullptr, nullptr);
  // 2. QKV projection (3-pass split, fused single launch)
  mx_gemm3g<16,24><<<384, 256, 0, stream>>>(h1h, h1l, qwh, qwl, qkvF, 3072, H_);
  // 3. RoPE apply + V transpose
  mx_rope_apply<<<dim3(T_/4, NH+NKV), 256, 0, stream>>>(qkvF, cosT, sinT, qh, ql, kh, kl);
  mx_transpose_v<<<dim3(NKV, T_/64), 256, 0, stream>>>(qkvF, vh, vl);
  // 4. attention (y<8) + MoE weight conversion helpers (y>=8, 3840 blocks)
  mx_attn<<<dim3(T_/64, 128), 512, 0, stream>>>(qh, ql, kh, kl, vh, vl, aoh, aol,
                                                w1, w3, w2, w1b, w3b, w2b);
  // 5. o_proj (3-pass split)
  mx_gemm3g<16,16><<<256, 256, 0, stream>>>(aoh, aol, woh, wol, oF, 2048, 2048);
  // 6. add + norm2 (residual output + h2 fp32 + h2 bf16); zero expert counts
  mx_addnorm<<<T_, 256, 0, stream>>>(oF, res1, ln2, outp + (size_t)T_*H_,
                                     nullptr, nullptr, h2f, h2b, meta);
  // 7. router + routing metadata (128-granular tiles)
  mx_router<<<T_, 256, 0, stream>>>(h2f, gatew, meta, tki, tkw);
  mx_scan<<<1, 256, 0, stream>>>(meta, perm, 7);
  mx_scatter<<<T_/256, 256, 0, stream>>>(tki, meta, perm, slot);
  // 8. MoE expert GEMMs
  mx_moe_w13<32><<<4096, 256, 0, stream>>>(h2b, w1b, w3b, Y1, perm, meta);
  mx_moe_w2k<16><<<2048, 256, 0, stream>>>(Y1, w2b, Y2, meta);
  // 9. combine weighted expert outputs -> out
  mx_combine<<<T_, 256, 0, stream>>>(Y2, slot, tkw, outp);
  (void)ws_size;
}

// Round 15
// 976.799 us; speedup vs baseline: 1.1119x; 1.0282x over previous
//
#include <hip/hip_runtime.h>
#include <hip/hip_bf16.h>
#include <math.h>

// Mixtral decoder layer, MI355X. T=2048 H=2048 NH=16 NKV=4 HD=128 I=4096 E=8 TOPK=2.
// Pre-router path (QKV, attn, o_proj): 3-pass bf16-split MFMA (~fp32 accurate) so the
// router top-k matches the fp32 reference; MoE expert path is plain bf16.
// R15: R14 + fusions: router folded into addnorm2 (h2f eliminated), 4 cvt_split
// launches -> 1, rope_apply+transpose_v -> 1 kernel.

#define T_  2048
#define H_  2048
#define NH  16
#define NKV 4
#define HD  128
#define II_ 4096
#define NE  8
#define EPS 1e-5f
#define PROWS 6144   // padded permuted rows

typedef __bf16 bf16x8 __attribute__((ext_vector_type(8)));
typedef float  f32x4  __attribute__((ext_vector_type(4)));
typedef unsigned short u16;

__device__ __forceinline__ u16 f2b(float f){ __bf16 b = (__bf16)f; return __builtin_bit_cast(u16, b); }
__device__ __forceinline__ float b2f(u16 u){ return (float)__builtin_bit_cast(__bf16, u); }

__device__ __forceinline__ void gll16(const void* g, void* l){
  __builtin_amdgcn_global_load_lds(
      (const __attribute__((address_space(1))) unsigned int*)g,
      (__attribute__((address_space(3))) unsigned int*)l, 16, 0, 0);
}

// ---------------- fused fp32 -> split (hi,lo) bf16 conversion of wq|wk|wv|wo ----------------
__global__ __launch_bounds__(256) void mx_cvt_split4(
    const float* __restrict__ wq, const float* __restrict__ wk,
    const float* __restrict__ wv, const float* __restrict__ wo,
    u16* __restrict__ qwh, u16* __restrict__ qwl,
    u16* __restrict__ woh, u16* __restrict__ wol)
{
  const int nq = 2048*2048/8, nk = 512*2048/8;
  const int total = nq + nk + nk + nq;
  int i = blockIdx.x*256 + threadIdx.x;
  int stride = gridDim.x*256;
  for (; i < total; i += stride){
    const float* s; u16 *hi, *lo; int j;
    if (i < nq)            { s = wq; hi = qwh;             lo = qwl;             j = i; }
    else if (i < nq+nk)    { s = wk; hi = qwh + 2048*2048; lo = qwl + 2048*2048; j = i - nq; }
    else if (i < nq+2*nk)  { s = wv; hi = qwh + 2560*2048; lo = qwl + 2560*2048; j = i - nq - nk; }
    else                   { s = wo; hi = woh;             lo = wol;             j = i - nq - 2*nk; }
    const f32x4* p = (const f32x4*)s + 2*(size_t)j;
    f32x4 a = p[0], b = p[1];
    uint4 uh, ul;
    u16 h0,h1,h2,h3;
    h0=f2b(a[0]); h1=f2b(a[1]); h2=f2b(a[2]); h3=f2b(a[3]);
    uh.x = (unsigned)h0 | ((unsigned)h1<<16);
    uh.y = (unsigned)h2 | ((unsigned)h3<<16);
    ul.x = (unsigned)f2b(a[0]-b2f(h0)) | ((unsigned)f2b(a[1]-b2f(h1))<<16);
    ul.y = (unsigned)f2b(a[2]-b2f(h2)) | ((unsigned)f2b(a[3]-b2f(h3))<<16);
    h0=f2b(b[0]); h1=f2b(b[1]); h2=f2b(b[2]); h3=f2b(b[3]);
    uh.z = (unsigned)h0 | ((unsigned)h1<<16);
    uh.w = (unsigned)h2 | ((unsigned)h3<<16);
    ul.z = (unsigned)f2b(b[0]-b2f(h0)) | ((unsigned)f2b(b[1]-b2f(h1))<<16);
    ul.w = (unsigned)f2b(b[2]-b2f(h2)) | ((unsigned)f2b(b[3]-b2f(h3))<<16);
    ((uint4*)hi)[j] = uh;
    ((uint4*)lo)[j] = ul;
  }
}

// ---------------- RoPE cos/sin table (double-precision inv_freq) ----------------
__global__ void mx_rope_table(const int* __restrict__ pos, float* __restrict__ cosT,
                              float* __restrict__ sinT)
{
  int i = blockIdx.x*256 + threadIdx.x;            // T*64
  int t = i >> 6, d = i & 63;
  float inv = (float)exp(-((double)d/64.0) * 9.210340371976184); // 10000^{-d/64}
  float f = (float)pos[t] * inv;
  cosT[i] = cosf(f); sinT[i] = sinf(f);
}

// ---------------- fused add + RMSNorm (split-bf16 out; zeroes meta counts) ----------------
__global__ __launch_bounds__(256) void mx_addnorm(
    const float* __restrict__ a, const float* __restrict__ b,
    const float* __restrict__ gam, float* __restrict__ res_out,
    u16* __restrict__ hi, u16* __restrict__ lo, int* __restrict__ mz)
{
  int t = blockIdx.x, tid = threadIdx.x;
  if (mz && t == 0 && tid < 8) mz[tid] = 0;
  const float4* A4 = (const float4*)a + (size_t)t*512;
  const float4* B4 = (const float4*)b + (size_t)t*512;
  float4 va = A4[tid], vb = B4[tid];
  float4 x0; x0.x=va.x+vb.x; x0.y=va.y+vb.y; x0.z=va.z+vb.z; x0.w=va.w+vb.w;
  va = A4[tid+256]; vb = B4[tid+256];
  float4 x1; x1.x=va.x+vb.x; x1.y=va.y+vb.y; x1.z=va.z+vb.z; x1.w=va.w+vb.w;
  float ss = x0.x*x0.x + x0.y*x0.y + x0.z*x0.z + x0.w*x0.w
           + x1.x*x1.x + x1.y*x1.y + x1.z*x1.z + x1.w*x1.w;
  #pragma unroll
  for (int d=32; d; d>>=1) ss += __shfl_down(ss, d);
  __shared__ float red[4];
  if ((tid&63)==0) red[tid>>6] = ss;
  __syncthreads();
  ss = red[0]+red[1]+red[2]+red[3];
  float scale = rsqrtf(ss * (1.f/2048.f) + EPS);
  float4* R4 = (float4*)res_out + (size_t)t*512;
  R4[tid] = x0; R4[tid+256] = x1;
  const float4* G4p = (const float4*)gam;
  float4 g0 = G4p[tid], g1 = G4p[tid+256];
  float4 y0; y0.x=x0.x*scale*g0.x; y0.y=x0.y*scale*g0.y; y0.z=x0.z*scale*g0.z; y0.w=x0.w*scale*g0.w;
  float4 y1; y1.x=x1.x*scale*g1.x; y1.y=x1.y*scale*g1.y; y1.z=x1.z*scale*g1.z; y1.w=x1.w*scale*g1.w;
  ushort4 uh, ul;
  uh.x=f2b(y0.x); ul.x=f2b(y0.x-b2f(uh.x));
  uh.y=f2b(y0.y); ul.y=f2b(y0.y-b2f(uh.y));
  uh.z=f2b(y0.z); ul.z=f2b(y0.z-b2f(uh.z));
  uh.w=f2b(y0.w); ul.w=f2b(y0.w-b2f(uh.w));
  ((ushort4*)hi)[(size_t)t*512 + tid] = uh; ((ushort4*)lo)[(size_t)t*512 + tid] = ul;
  uh.x=f2b(y1.x); ul.x=f2b(y1.x-b2f(uh.x));
  uh.y=f2b(y1.y); ul.y=f2b(y1.y-b2f(uh.y));
  uh.z=f2b(y1.z); ul.z=f2b(y1.z-b2f(uh.z));
  uh.w=f2b(y1.w); ul.w=f2b(y1.w-b2f(uh.w));
  ((ushort4*)hi)[(size_t)t*512 + tid+256] = uh; ((ushort4*)lo)[(size_t)t*512 + tid+256] = ul;
}

// ------- fused add + RMSNorm + router (top-2) : h2 bf16 out, no fp32 h2 buffer -------
__global__ __launch_bounds__(256) void mx_addnorm_router(
    const float* __restrict__ a, const float* __restrict__ b,
    const float* __restrict__ gam, float* __restrict__ res_out,
    u16* __restrict__ hbf,
    const float* __restrict__ gw, int* __restrict__ meta,
    int* __restrict__ tki, float* __restrict__ tkw)
{
  int t = blockIdx.x, tid = threadIdx.x;
  const float4* A4 = (const float4*)a + (size_t)t*512;
  const float4* B4 = (const float4*)b + (size_t)t*512;
  float4 va = A4[tid], vb = B4[tid];
  float4 x0; x0.x=va.x+vb.x; x0.y=va.y+vb.y; x0.z=va.z+vb.z; x0.w=va.w+vb.w;
  va = A4[tid+256]; vb = B4[tid+256];
  float4 x1; x1.x=va.x+vb.x; x1.y=va.y+vb.y; x1.z=va.z+vb.z; x1.w=va.w+vb.w;
  float ss = x0.x*x0.x + x0.y*x0.y + x0.z*x0.z + x0.w*x0.w
           + x1.x*x1.x + x1.y*x1.y + x1.z*x1.z + x1.w*x1.w;
  #pragma unroll
  for (int d=32; d; d>>=1) ss += __shfl_down(ss, d);
  __shared__ float red[4];
  __shared__ float redr[4][8];
  if ((tid&63)==0) red[tid>>6] = ss;
  __syncthreads();
  ss = red[0]+red[1]+red[2]+red[3];
  float scale = rsqrtf(ss * (1.f/2048.f) + EPS);
  float4* R4 = (float4*)res_out + (size_t)t*512;
  R4[tid] = x0; R4[tid+256] = x1;
  const float4* G4p = (const float4*)gam;
  float4 g0 = G4p[tid], g1 = G4p[tid+256];
  float4 y0; y0.x=x0.x*scale*g0.x; y0.y=x0.y*scale*g0.y; y0.z=x0.z*scale*g0.z; y0.w=x0.w*scale*g0.w;
  float4 y1; y1.x=x1.x*scale*g1.x; y1.y=x1.y*scale*g1.y; y1.z=x1.z*scale*g1.z; y1.w=x1.w*scale*g1.w;
  ushort4 u0; u0.x=f2b(y0.x); u0.y=f2b(y0.y); u0.z=f2b(y0.z); u0.w=f2b(y0.w);
  ushort4 u1; u1.x=f2b(y1.x); u1.y=f2b(y1.y); u1.z=f2b(y1.z); u1.w=f2b(y1.w);
  ((ushort4*)hbf)[(size_t)t*512 + tid] = u0; ((ushort4*)hbf)[(size_t)t*512 + tid+256] = u1;

  // ---- router logits from the fp32 y registers (identical math to fp32-h2 path) ----
  const float4* GW = (const float4*)gw;    // [E][512] float4
  float p[8];
  #pragma unroll
  for (int e=0;e<8;e++){
    float4 ga = GW[e*512 + tid];
    float4 gb = GW[e*512 + 256 + tid];
    p[e] = y0.x*ga.x + y0.y*ga.y + y0.z*ga.z + y0.w*ga.w
         + y1.x*gb.x + y1.y*gb.y + y1.z*gb.z + y1.w*gb.w;
  }
  #pragma unroll
  for (int e=0;e<8;e++)
    #pragma unroll
    for (int d=32; d; d>>=1) p[e] += __shfl_down(p[e], d);
  int w = tid>>6;
  if ((tid&63)==0){
    #pragma unroll
    for (int e=0;e<8;e++) redr[w][e] = p[e];
  }
  __syncthreads();
  if (tid==0){
    float lg[8];
    #pragma unroll
    for (int e=0;e<8;e++) lg[e] = redr[0][e]+redr[1][e]+redr[2][e]+redr[3][e];
    int e0 = 0;
    for (int e=1;e<8;e++) if (lg[e] > lg[e0]) e0 = e;
    int e1 = (e0==0)?1:0;
    for (int e=0;e<8;e++) if (e!=e0 && lg[e] > lg[e1]) e1 = e;
    float w0 = 1.f/(1.f + __expf(lg[e1]-lg[e0]));
    tki[t*2]=e0; tki[t*2+1]=e1; tkw[t*2]=w0; tkw[t*2+1]=1.f-w0;
    atomicAdd(&meta[e0],1); atomicAdd(&meta[e1],1);
  }
}

// ------- 3-pass split GEMM, gll16 m97 skeleton: C = A(hi,lo) x B(hi,lo)^T, fp32 out -------
template<int NX, int NY>
__global__ __launch_bounds__(256,2) void mx_gemm3g(
    const u16* __restrict__ Ah, const u16* __restrict__ Al,
    const u16* __restrict__ Bh, const u16* __restrict__ Bl,
    float* __restrict__ C, int ldc, int K)
{
  __shared__ u16 AhS[128*64], AlS[128*64], BhS[128*64], BlS[128*64];
  int bid = blockIdx.x;
  int xcd = bid & 7, j = bid >> 3;
  int x = j % NX, p = j / NX;
  int y = xcd + 8*p;
  int m0 = x*128, n0 = y*128;
  int tid = threadIdx.x;
  int w = tid>>6, lane = tid&63, wr = w>>1, wc = w&1, g = lane>>4, lr = lane&15;
  f32x4 acc[4][4];
  #pragma unroll
  for (int fm=0;fm<4;fm++)
    #pragma unroll
    for (int fn=0;fn<4;fn++) acc[fm][fn] = (f32x4){0.f,0.f,0.f,0.f};

  for (int k0 = 0; k0 < K; k0 += 64) {
    #pragma unroll
    for (int i=0;i<4;i++){
      int c = i*256 + tid, r = c>>3, ch = c&7;
      int sw = ((ch ^ (r&7))<<3);
      int db = (i*256 + w*64)<<3;
      gll16(Ah + (size_t)(m0+r)*K + k0 + sw, &AhS[db]);
      gll16(Al + (size_t)(m0+r)*K + k0 + sw, &AlS[db]);
      gll16(Bh + (size_t)(n0+r)*K + k0 + sw, &BhS[db]);
      gll16(Bl + (size_t)(n0+r)*K + k0 + sw, &BlS[db]);
    }
    __syncthreads();
    #pragma unroll
    for (int kk=0;kk<2;kk++){
      bf16x8 ah[4], al[4], bh[4], bl[4];
      #pragma unroll
      for (int fm=0;fm<4;fm++){
        int r = wr*64 + fm*16 + lr;
        int ch = ((kk<<2)+g) ^ (r&7);
        ah[fm] = *(const bf16x8*)(&AhS[(r<<6)+(ch<<3)]);
        al[fm] = *(const bf16x8*)(&AlS[(r<<6)+(ch<<3)]);
      }
      #pragma unroll
      for (int fn=0;fn<4;fn++){
        int r = wc*64 + fn*16 + lr;
        int ch = ((kk<<2)+g) ^ (r&7);
        bh[fn] = *(const bf16x8*)(&BhS[(r<<6)+(ch<<3)]);
        bl[fn] = *(const bf16x8*)(&BlS[(r<<6)+(ch<<3)]);
      }
      __builtin_amdgcn_s_setprio(1);
      #pragma unroll
      for (int fm=0;fm<4;fm++)
        #pragma unroll
        for (int fn=0;fn<4;fn++){
          acc[fm][fn] = __builtin_amdgcn_mfma_f32_16x16x32_bf16(ah[fm], bh[fn], acc[fm][fn],0,0,0);
          acc[fm][fn] = __builtin_amdgcn_mfma_f32_16x16x32_bf16(ah[fm], bl[fn], acc[fm][fn],0,0,0);
          acc[fm][fn] = __builtin_amdgcn_mfma_f32_16x16x32_bf16(al[fm], bh[fn], acc[fm][fn],0,0,0);
        }
      __builtin_amdgcn_s_setprio(0);
    }
    __syncthreads();
  }
  #pragma unroll
  for (int fm=0;fm<4;fm++)
    #pragma unroll
    for (int fn=0;fn<4;fn++)
      #pragma unroll
      for (int i=0;i<4;i++){
        size_t rg = (size_t)(m0 + wr*64 + fm*16 + g*4 + i);
        int cg = n0 + wc*64 + fn*16 + lr;
        C[rg*ldc + cg] = acc[fm][fn][i];
      }
}

// ------------- MoE w1+w3 fused GEMM + silu epilogue (all-bf16, m97-style) -------------
template<int NY>
__global__ __launch_bounds__(256,2) void mx_moe_w13(
    const u16* __restrict__ A,
    const u16* __restrict__ B1, const u16* __restrict__ B3,
    u16* __restrict__ Y,
    const int* __restrict__ row_map, const int* __restrict__ meta)
{
  __shared__ u16 As[128*64], B1s[128*64], B3s[128*64];
  int bid = blockIdx.x;
  int xcd = bid & 7, j = bid >> 3;
  int x = j & 15, p = j >> 4;
  int panel = xcd + 8*p;                 // < NE*NY
  int e = panel / NY, y = panel % NY;
  if (x >= meta[16+e]) return;
  int rowbase = meta[8+e] + (x<<7);
  const u16* B1p = B1 + ((size_t)e*II_ + y*128)*H_;
  const u16* B3p = B3 + ((size_t)e*II_ + y*128)*H_;
  int tid = threadIdx.x;
  int w = tid>>6, lane = tid&63, wr = w>>1, wc = w&1, g = lane>>4, lr = lane&15;

  f32x4 acc1[4][4], acc3[4][4];
  #pragma unroll
  for (int fm=0;fm<4;fm++)
    #pragma unroll
    for (int fn=0;fn<4;fn++){ acc1[fm][fn]=(f32x4){0,0,0,0}; acc3[fm][fn]=(f32x4){0,0,0,0}; }

  for (int k0 = 0; k0 < H_; k0 += 64) {
    #pragma unroll
    for (int i=0;i<4;i++){
      int c = i*256 + tid, r = c>>3, ch = c&7;
      int sw = (ch ^ (r&7))<<3;
      int db = (i*256 + w*64)<<3;
      int grow = row_map[rowbase + r];
      gll16(A   + (size_t)grow*H_ + k0 + sw, &As[db]);
      gll16(B1p + (size_t)r*H_    + k0 + sw, &B1s[db]);
      gll16(B3p + (size_t)r*H_    + k0 + sw, &B3s[db]);
    }
    __syncthreads();
    #pragma unroll
    for (int kk=0;kk<2;kk++){
      bf16x8 af[4], b1f[4], b3f[4];
      #pragma unroll
      for (int fm=0;fm<4;fm++){
        int r = wr*64 + fm*16 + lr;
        int ch = ((kk<<2)+g) ^ (r&7);
        af[fm] = *(const bf16x8*)(&As[(r<<6)+(ch<<3)]);
      }
      #pragma unroll
      for (int fn=0;fn<4;fn++){
        int r = wc*64 + fn*16 + lr;
        int ch = ((kk<<2)+g) ^ (r&7);
        b1f[fn] = *(const bf16x8*)(&B1s[(r<<6)+(ch<<3)]);
        b3f[fn] = *(const bf16x8*)(&B3s[(r<<6)+(ch<<3)]);
      }
      __builtin_amdgcn_s_setprio(1);
      #pragma unroll
      for (int fm=0;fm<4;fm++)
        #pragma unroll
        for (int fn=0;fn<4;fn++){
          acc1[fm][fn] = __builtin_amdgcn_mfma_f32_16x16x32_bf16(af[fm], b1f[fn], acc1[fm][fn],0,0,0);
          acc3[fm][fn] = __builtin_amdgcn_mfma_f32_16x16x32_bf16(af[fm], b3f[fn], acc3[fm][fn],0,0,0);
        }
      __builtin_amdgcn_s_setprio(0);
    }
    __syncthreads();
  }
  int n0 = y*128 + wc*64;
  #pragma unroll
  for (int fm=0;fm<4;fm++)
    #pragma unroll
    for (int fn=0;fn<4;fn++)
      #pragma unroll
      for (int i=0;i<4;i++){
        size_t rg = (size_t)(rowbase + wr*64 + fm*16 + g*4 + i);
        int cg = n0 + fn*16 + lr;
        float gg = acc1[fm][fn][i], uu = acc3[fm][fn][i];
        float sg = gg / (1.f + __expf(-gg));
        Y[rg*II_ + cg] = f2b(sg * uu);
      }
}

// ------------- MoE w2 GEMM (all-bf16, m97-style): Y2(bf16) = Y . w2^T -------------
template<int NY>
__global__ __launch_bounds__(256,2) void mx_moe_w2k(
    const u16* __restrict__ A,       // Y bf16 [PROWS][II_]
    const u16* __restrict__ B,       // w2b bf16 [E][H_][II_]
    u16* __restrict__ C,             // Y2 bf16 [PROWS][H_]
    const int* __restrict__ meta)
{
  __shared__ u16 As[128*64], Bs[128*64];
  int bid = blockIdx.x;
  int xcd = bid & 7, j = bid >> 3;
  int x = j & 15, p = j >> 4;
  int panel = xcd + 8*p;                 // < NE*NY
  int e = panel / NY, y = panel % NY;
  if (x >= meta[16+e]) return;
  int rowbase = meta[8+e] + (x<<7);
  const u16* Bp = B + ((size_t)e*H_ + y*128)*II_;
  int tid = threadIdx.x;
  int w = tid>>6, lane = tid&63, wr = w>>1, wc = w&1, g = lane>>4, lr = lane&15;

  f32x4 acc[4][4];
  #pragma unroll
  for (int fm=0;fm<4;fm++)
    #pragma unroll
    for (int fn=0;fn<4;fn++) acc[fm][fn] = (f32x4){0,0,0,0};

  for (int k0 = 0; k0 < II_; k0 += 64) {
    #pragma unroll
    for (int i=0;i<4;i++){
      int c = i*256 + tid, r = c>>3, ch = c&7;
      int sw = (ch ^ (r&7))<<3;
      int db = (i*256 + w*64)<<3;
      gll16(A  + (size_t)(rowbase + r)*II_ + k0 + sw, &As[db]);
      gll16(Bp + (size_t)r*II_             + k0 + sw, &Bs[db]);
    }
    __syncthreads();
    #pragma unroll
    for (int kk=0;kk<2;kk++){
      bf16x8 af[4], bf[4];
      #pragma unroll
      for (int fm=0;fm<4;fm++){
        int r = wr*64 + fm*16 + lr;
        int ch = ((kk<<2)+g) ^ (r&7);
        af[fm] = *(const bf16x8*)(&As[(r<<6)+(ch<<3)]);
      }
      #pragma unroll
      for (int fn=0;fn<4;fn++){
        int r = wc*64 + fn*16 + lr;
        int ch = ((kk<<2)+g) ^ (r&7);
        bf[fn] = *(const bf16x8*)(&Bs[(r<<6)+(ch<<3)]);
      }
      __builtin_amdgcn_s_setprio(1);
      #pragma unroll
      for (int fm=0;fm<4;fm++)
        #pragma unroll
        for (int fn=0;fn<4;fn++)
          acc[fm][fn] = __builtin_amdgcn_mfma_f32_16x16x32_bf16(af[fm], bf[fn], acc[fm][fn],0,0,0);
      __builtin_amdgcn_s_setprio(0);
    }
    __syncthreads();
  }
  int n0 = y*128 + wc*64;
  #pragma unroll
  for (int fm=0;fm<4;fm++)
    #pragma unroll
    for (int fn=0;fn<4;fn++)
      #pragma unroll
      for (int i=0;i<4;i++){
        size_t rg = (size_t)(rowbase + wr*64 + fm*16 + g*4 + i);
        int cg = n0 + fn*16 + lr;
        C[rg*H_ + cg] = f2b(acc[fm][fn][i]);
      }
}

// -------- fused RoPE apply (y<20) + V transpose (y>=20): qkv fp32 -> split-bf16 --------
__global__ __launch_bounds__(256) void mx_rope_trans(const float* __restrict__ qkv,
    const float* __restrict__ cosT, const float* __restrict__ sinT,
    u16* __restrict__ qh, u16* __restrict__ ql, u16* __restrict__ kh, u16* __restrict__ kl,
    u16* __restrict__ vh, u16* __restrict__ vl)
{
  __shared__ float tile[64][132];
  int yb = blockIdx.y;
  if (yb < NH+NKV){
    // ---- RoPE path ----
    int t = blockIdx.x*4 + (threadIdx.x>>6);
    int hh = yb, d = threadIdx.x & 63;
    const float* row = qkv + (size_t)t*3072;
    float c = cosT[t*64+d], s = sinT[t*64+d];
    float x1, x2; size_t base; u16 *oh, *ol;
    if (hh < NH){ x1 = row[hh*HD+d]; x2 = row[hh*HD+d+64];
       base = ((size_t)hh*T_ + t)*HD; oh = qh; ol = ql; }
    else { int kvh = hh-NH; x1 = row[2048 + kvh*HD + d]; x2 = row[2048 + kvh*HD + d + 64];
       base = ((size_t)kvh*T_ + t)*HD; oh = kh; ol = kl; }
    float o1 = x1*c - x2*s, o2 = x2*c + x1*s;
    u16 a = f2b(o1); oh[base+d]    = a; ol[base+d]    = f2b(o1 - b2f(a));
    u16 b = f2b(o2); oh[base+d+64] = b; ol[base+d+64] = f2b(o2 - b2f(b));
    return;
  }
  // ---- V transpose path ----
  if ((int)blockIdx.x >= T_/64) return;
  int kv = yb - (NH+NKV), t0 = blockIdx.x*64, tid = threadIdx.x;
  #pragma unroll
  for (int it=0; it<32; ++it){
    int idx = it*256 + tid; int r = idx>>7, d = idx&127;
    tile[r][d] = qkv[(size_t)(t0+r)*3072 + 2560 + kv*HD + d];
  }
  __syncthreads();
  #pragma unroll
  for (int it=0; it<32; ++it){
    int idx = it*256 + tid; int d = idx>>6, j = idx&63;
    float x = tile[j][d];
    u16 a = f2b(x);
    size_t o = ((size_t)kv*HD + d)*T_ + t0 + j;
    vh[o] = a; vl[o] = f2b(x - b2f(a));
  }
}

// ---------------- flash attention (y<8) + weight-cvt helper blocks (y>=8) ----------------
// Attention: 2 heads/block, 8 waves, dbuf 160KB LDS, counted vmcnt(8) (R11-proven).
// Helpers: grid-stride fp32->bf16 conversion of w1/w3/w2 — backfill CUs idled by
// causal imbalance (attn blocks dispatch first: lower linear IDs).
__global__ __launch_bounds__(512) void mx_attn(
  const u16* __restrict__ qh_, const u16* __restrict__ ql_,
  const u16* __restrict__ kh_, const u16* __restrict__ kl_,
  const u16* __restrict__ vh_, const u16* __restrict__ vl_,
  u16* __restrict__ oh_, u16* __restrict__ ol_,
  const float* __restrict__ w1f, const float* __restrict__ w3f,
  const float* __restrict__ w2f,
  u16* __restrict__ w1b, u16* __restrict__ w3b, u16* __restrict__ w2b)
{
  if (blockIdx.y >= 8){
    // -------- cvt helper path (no LDS, no barriers) --------
    const int n8 = NE*II_*H_/8;                       // 8388608 per matrix
    int hb = (blockIdx.y - 8)*gridDim.x + blockIdx.x; // 0..3839
    int i  = hb*512 + threadIdx.x;
    const int stride = 3840*512;
    for (; i < 3*n8; i += stride){
      const float* s; u16* d; int j;
      if (i < n8)        { s = w1f; d = w1b; j = i; }
      else if (i < 2*n8) { s = w3f; d = w3b; j = i - n8; }
      else               { s = w2f; d = w2b; j = i - 2*n8; }
      const f32x4* p = (const f32x4*)s + 2*(size_t)j;
      f32x4 a = p[0], b = p[1];
      uint4 u;
      u.x = (unsigned)f2b(a[0]) | ((unsigned)f2b(a[1])<<16);
      u.y = (unsigned)f2b(a[2]) | ((unsigned)f2b(a[3])<<16);
      u.z = (unsigned)f2b(b[0]) | ((unsigned)f2b(b[1])<<16);
      u.w = (unsigned)f2b(b[2]) | ((unsigned)f2b(b[3])<<16);
      ((uint4*)d)[j] = u;
    }
    return;
  }

  int pair = blockIdx.y;                    // 0..7 -> heads (2p, 2p+1)
  int kvh = pair >> 1;
  int qt = (pair & 4) ? (31 - (int)blockIdx.x) : (int)blockIdx.x;
  int tid = threadIdx.x, w = tid>>6, lane = tid&63, g = lane>>4, lr = lane&15;
  int head = pair*2 + (w>>2);
  int q0 = qt*64 + (w&3)*16;
  __shared__ u16 KV[2][4][8192];            // [buf][Kh,Kl,Vh,Vl] 128 KB
  __shared__ u16 Ph[8][1024], Pl[8][1024];  // 32 KB (per-wave)

  bf16x8 qfh[4], qfl[4];
  const u16* qrh = qh_ + ((size_t)head*T_ + q0 + lr)*HD;
  const u16* qrl = ql_ + ((size_t)head*T_ + q0 + lr)*HD;
  #pragma unroll
  for (int kk=0;kk<4;kk++){
    qfh[kk] = *(const bf16x8*)(qrh + kk*32 + g*8);
    qfl[kk] = *(const bf16x8*)(qrl + kk*32 + g*8);
  }
  f32x4 o[8];
  #pragma unroll
  for (int nf=0;nf<8;nf++) o[nf] = (f32x4){0.f,0.f,0.f,0.f};
  float mreg[4] = {-3e38f,-3e38f,-3e38f,-3e38f}, lsum[4] = {0.f,0.f,0.f,0.f};

  const u16* kbase = kh_ + (size_t)kvh*T_*HD;
  const u16* lbase = kl_ + (size_t)kvh*T_*HD;
  const u16* vbase = vh_ + (size_t)kvh*HD*T_;
  const u16* wbase = vl_ + (size_t)kvh*HD*T_;

  auto stage = [&](int buf, int kvb){
    #pragma unroll
    for (int i=0;i<2;i++){
      int cb = i*512 + w*64;                // wave-uniform chunk base (0..1023)
      int c  = cb + lane;
      int kr = c>>4, kc = ((c&15) ^ (kr&7))<<3;
      gll16(kbase + (size_t)(kvb+kr)*HD + kc, &KV[buf][0][cb*8]);
      gll16(lbase + (size_t)(kvb+kr)*HD + kc, &KV[buf][1][cb*8]);
      int vr = c>>3, vc = ((c&7) ^ (vr&7))<<3;
      gll16(vbase + (size_t)vr*T_ + kvb + vc, &KV[buf][2][cb*8]);
      gll16(wbase + (size_t)vr*T_ + kvb + vc, &KV[buf][3][cb*8]);
    }
  };

  stage(0, 0);      // prologue: 8 loads/thread in flight

  for (int kt = 0; kt <= qt; ++kt) {
    int cur = kt & 1;
    int kvb = kt*64;
    if (kt < qt) {
      stage(cur^1, kvb+64);
      asm volatile("s_waitcnt vmcnt(8)" ::: "memory");   // cur tile landed, next in flight
    } else {
      asm volatile("s_waitcnt vmcnt(0)" ::: "memory");
    }
    __builtin_amdgcn_s_barrier();

    // ---- QK^T (3-pass split) from LDS ----
    f32x4 s[4];
    #pragma unroll
    for (int nf=0;nf<4;nf++) s[nf] = (f32x4){0.f,0.f,0.f,0.f};
    __builtin_amdgcn_s_setprio(1);
    #pragma unroll
    for (int nf=0; nf<4; nf++){
      int row = nf*16 + lr;
      #pragma unroll
      for (int kk=0;kk<4;kk++){
        int off = row*128 + ((((kk<<2)+g) ^ (lr&7))<<3);
        bf16x8 kf = *(const bf16x8*)(&KV[cur][0][off]);
        bf16x8 kg = *(const bf16x8*)(&KV[cur][1][off]);
        s[nf] = __builtin_amdgcn_mfma_f32_16x16x32_bf16(qfh[kk], kf, s[nf],0,0,0);
        s[nf] = __builtin_amdgcn_mfma_f32_16x16x32_bf16(qfh[kk], kg, s[nf],0,0,0);
        s[nf] = __builtin_amdgcn_mfma_f32_16x16x32_bf16(qfl[kk], kf, s[nf],0,0,0);
      }
    }
    __builtin_amdgcn_s_setprio(0);

    // ---- online softmax ----
    float sv[4][4], pm[4];
    #pragma unroll
    for (int i=0;i<4;i++) pm[i] = -3e38f;
    bool diag = (kt == qt);
    #pragma unroll
    for (int nf=0;nf<4;nf++)
      #pragma unroll
      for (int i=0;i<4;i++){
        float v = s[nf][i] * 0.08838834764831845f;
        if (diag && (kvb + nf*16 + lr > q0 + g*4 + i)) v = -1e30f;
        sv[nf][i] = v;
        pm[i] = fmaxf(pm[i], v);
      }
    #pragma unroll
    for (int i=0;i<4;i++)
      #pragma unroll
      for (int d=1; d<16; d<<=1) pm[i] = fmaxf(pm[i], __shfl_xor(pm[i], d));
    float sf[4], psum[4];
    #pragma unroll
    for (int i=0;i<4;i++){
      float nm = fmaxf(mreg[i], pm[i]);
      sf[i] = __expf(mreg[i] - nm);
      mreg[i] = nm; psum[i] = 0.f;
    }
    #pragma unroll
    for (int nf=0;nf<4;nf++)
      #pragma unroll
      for (int i=0;i<4;i++){
        float e = __expf(sv[nf][i] - mreg[i]);
        sv[nf][i] = e; psum[i] += e;
      }
    #pragma unroll
    for (int i=0;i<4;i++){
      #pragma unroll
      for (int d=1; d<16; d<<=1) psum[i] += __shfl_xor(psum[i], d);
      lsum[i] = lsum[i]*sf[i] + psum[i];
    }
    #pragma unroll
    for (int nf=0;nf<8;nf++)
      #pragma unroll
      for (int i=0;i<4;i++) o[nf][i] *= sf[i];

    // ---- P round-trip (per-wave LDS, no barrier needed) ----
    #pragma unroll
    for (int nf=0;nf<4;nf++)
      #pragma unroll
      for (int i=0;i<4;i++){
        int qi = g*4 + i, kv = nf*16 + lr;
        int idx = qi*64 + (kv ^ ((qi&7)<<3));
        u16 hb = f2b(sv[nf][i]);
        Ph[w][idx] = hb;
        Pl[w][idx] = f2b(sv[nf][i] - b2f(hb));
      }

    // ---- PV (3-pass split) from LDS ----
    #pragma unroll
    for (int kk2=0; kk2<2; kk2++){
      int pidx = lr*64 + ((kk2*32 + g*8) ^ ((lr&7)<<3));
      bf16x8 ph = *(const bf16x8*)(&Ph[w][pidx]);
      bf16x8 pl = *(const bf16x8*)(&Pl[w][pidx]);
      __builtin_amdgcn_s_setprio(1);
      #pragma unroll
      for (int nf=0; nf<8; nf++){
        int row = nf*16 + lr;
        int off = row*64 + ((((kk2<<2)+g) ^ (lr&7))<<3);
        bf16x8 vf = *(const bf16x8*)(&KV[cur][2][off]);
        bf16x8 vg = *(const bf16x8*)(&KV[cur][3][off]);
        o[nf] = __builtin_amdgcn_mfma_f32_16x16x32_bf16(ph, vf, o[nf],0,0,0);
        o[nf] = __builtin_amdgcn_mfma_f32_16x16x32_bf16(ph, vg, o[nf],0,0,0);
        o[nf] = __builtin_amdgcn_mfma_f32_16x16x32_bf16(pl, vf, o[nf],0,0,0);
      }
      __builtin_amdgcn_s_setprio(0);
    }
    __builtin_amdgcn_s_barrier();   // all waves done with buf[cur] before overwrite
  }

  float inv[4];
  #pragma unroll
  for (int i=0;i<4;i++) inv[i] = 1.0f / lsum[i];
  #pragma unroll
  for (int nf=0;nf<8;nf++)
    #pragma unroll
    for (int i=0;i<4;i++){
      float v = o[nf][i] * inv[i];
      size_t oidx = (size_t)(q0 + g*4 + i)*2048 + head*HD + nf*16 + lr;
      u16 hb = f2b(v);
      oh_[oidx] = hb; ol_[oidx] = f2b(v - b2f(hb));
    }
}

// meta: [0..7]=counts [8..15]=poff [16..23]=ptiles [24..31]=cursor; gsh = tile granularity shift
__global__ void mx_scan(int* __restrict__ meta, int* __restrict__ perm, int gsh)
{
  if (threadIdx.x == 0){
    int run = 0;
    for (int e=0;e<8;e++){
      meta[8+e] = run;
      int pt = (meta[e] + (1<<gsh) - 1) >> gsh;
      meta[16+e] = pt;
      run += pt << gsh;
      meta[24+e] = 0;
    }
  }
  for (int i = threadIdx.x; i < PROWS; i += 256) perm[i] = 0;
}

__global__ void mx_scatter(const int* __restrict__ tki, int* __restrict__ meta,
                           int* __restrict__ perm, int* __restrict__ slot)
{
  int t = blockIdx.x*256 + threadIdx.x;
  if (t >= T_) return;
  #pragma unroll
  for (int j=0;j<2;j++){
    int e = tki[t*2+j];
    int s = atomicAdd(&meta[24+e], 1);
    int pos = meta[8+e] + s;
    perm[pos] = t;
    slot[t*2+j] = pos;
  }
}

__global__ void mx_combine(const u16* __restrict__ Y2, const int* __restrict__ slot,
                           const float* __restrict__ tkw, float* __restrict__ out)
{
  int t = blockIdx.x, tid = threadIdx.x;
  int s0 = slot[t*2], s1 = slot[t*2+1];
  float w0 = tkw[t*2], w1 = tkw[t*2+1];
  const uint4* r0 = (const uint4*)(Y2 + (size_t)s0*H_);
  const uint4* r1 = (const uint4*)(Y2 + (size_t)s1*H_);
  float4* o4 = (float4*)(out + (size_t)t*H_);
  {
    int i = tid;
    uint4 a = r0[i], b = r1[i];
    const u16* ap = (const u16*)&a;
    const u16* bp = (const u16*)&b;
    float4 c0, c1;
    c0.x = w0*b2f(ap[0]) + w1*b2f(bp[0]);
    c0.y = w0*b2f(ap[1]) + w1*b2f(bp[1]);
    c0.z = w0*b2f(ap[2]) + w1*b2f(bp[2]);
    c0.w = w0*b2f(ap[3]) + w1*b2f(bp[3]);
    c1.x = w0*b2f(ap[4]) + w1*b2f(bp[4]);
    c1.y = w0*b2f(ap[5]) + w1*b2f(bp[5]);
    c1.z = w0*b2f(ap[6]) + w1*b2f(bp[6]);
    c1.w = w0*b2f(ap[7]) + w1*b2f(bp[7]);
    o4[i*2]   = c0;
    o4[i*2+1] = c1;
  }
}

extern "C" void kernel_launch(void* const* d_in, const int* in_sizes, int n_in,
                              void* d_out, int out_size, void* d_ws, size_t ws_size,
                              hipStream_t stream)
{
  (void)in_sizes; (void)n_in; (void)out_size;
  const int*   positions = (const int*)  d_in[0];
  const float* hidden    = (const float*)d_in[1];
  const float* residual  = (const float*)d_in[2];
  const float* ln1       = (const float*)d_in[3];
  const float* ln2       = (const float*)d_in[4];
  const float* wq        = (const float*)d_in[5];
  const float* wk        = (const float*)d_in[6];
  const float* wv        = (const float*)d_in[7];
  const float* wo        = (const float*)d_in[8];
  const float* gatew     = (const float*)d_in[9];
  const float* w1        = (const float*)d_in[10];
  const float* w3        = (const float*)d_in[11];
  const float* w2        = (const float*)d_in[12];
  float* outp = (float*)d_out;                 // [T*H] moe out, then [T*H] residual
  char* ws = (char*)d_ws;

  size_t off = 0;
  auto alloc = [&](size_t n){ size_t o = off; off += (n + 255) & ~(size_t)255; return o; };
  float* cosT = (float*)(ws + alloc((size_t)T_*64*4));
  float* sinT = (float*)(ws + alloc((size_t)T_*64*4));
  size_t res1_off = alloc((size_t)T_*H_*4);
  float* res1 = (float*)(ws + res1_off);
  u16*   h1h  = (u16*)  (ws + alloc((size_t)T_*H_*2));
  u16*   h1l  = (u16*)  (ws + alloc((size_t)T_*H_*2));
  float* qkvF = (float*)(ws + alloc((size_t)T_*3072*4));
  size_t qh_off = alloc((size_t)NH*T_*HD*2);
  u16*   qh   = (u16*)  (ws + qh_off);
  u16*   ql   = (u16*)  (ws + alloc((size_t)NH*T_*HD*2));
  u16*   kh   = (u16*)  (ws + alloc((size_t)NKV*T_*HD*2));
  u16*   kl   = (u16*)  (ws + alloc((size_t)NKV*T_*HD*2));
  u16*   vh   = (u16*)  (ws + alloc((size_t)NKV*T_*HD*2));
  u16*   vl   = (u16*)  (ws + alloc((size_t)NKV*T_*HD*2));
  u16*   aoh  = (u16*)  (ws + alloc((size_t)T_*2048*2));
  u16*   aol  = (u16*)  (ws + alloc((size_t)T_*2048*2));
  float* oF   = (float*)(ws + alloc((size_t)T_*H_*4));
  u16*   h2b  = (u16*)  (ws + alloc((size_t)T_*H_*2));
  int*   meta = (int*)  (ws + alloc(32*4));
  int*   tki  = (int*)  (ws + alloc((size_t)T_*2*4));
  float* tkw  = (float*)(ws + alloc((size_t)T_*2*4));
  int*   slot = (int*)  (ws + alloc((size_t)T_*2*4));
  int*   perm = (int*)  (ws + alloc((size_t)PROWS*4));
  u16*   Y1   = (u16*)  (ws + alloc((size_t)PROWS*II_*2));
  // Y2 (bf16) aliases qh..oF region (dead before the w2 GEMM)
  u16*   Y2   = (u16*)(ws + qh_off);
  u16* w1b = (u16*)(ws + alloc((size_t)NE*II_*H_*2));
  u16* w3b = (u16*)(ws + alloc((size_t)NE*II_*H_*2));
  u16* w2b = (u16*)(ws + alloc((size_t)NE*H_*II_*2));
  u16* qwh = (u16*)(ws + alloc((size_t)3072*H_*2));   // wq|wk|wv rows concat, split-hi
  u16* qwl = (u16*)(ws + alloc((size_t)3072*H_*2));
  u16* woh = (u16*)(ws + alloc((size_t)H_*H_*2));
  u16* wol = (u16*)(ws + alloc((size_t)H_*H_*2));

  // 0. attention-path weight conversions (single fused launch)
  mx_cvt_split4<<<1024, 256, 0, stream>>>(wq, wk, wv, wo, qwh, qwl, woh, wol);
  // 1. RoPE tables + fused add+norm1 (also zeroes expert counts)
  mx_rope_table<<<512, 256, 0, stream>>>(positions, cosT, sinT);
  mx_addnorm<<<T_, 256, 0, stream>>>(hidden, residual, ln1, res1, h1h, h1l, meta);
  // 2. QKV projection (3-pass split, fused single launch)
  mx_gemm3g<16,24><<<384, 256, 0, stream>>>(h1h, h1l, qwh, qwl, qkvF, 3072, H_);
  // 3. RoPE apply + V transpose (fused)
  mx_rope_trans<<<dim3(T_/4, NH+NKV+NKV), 256, 0, stream>>>(qkvF, cosT, sinT,
                                                            qh, ql, kh, kl, vh, vl);
  // 4. attention (y<8) + MoE weight conversion helpers (y>=8, 3840 blocks)
  mx_attn<<<dim3(T_/64, 128), 512, 0, stream>>>(qh, ql, kh, kl, vh, vl, aoh, aol,
                                                w1, w3, w2, w1b, w3b, w2b);
  // 5. o_proj (3-pass split)
  mx_gemm3g<16,16><<<256, 256, 0, stream>>>(aoh, aol, woh, wol, oF, 2048, 2048);
  // 6. add + norm2 + router fused (residual output + h2 bf16 + top-2)
  mx_addnorm_router<<<T_, 256, 0, stream>>>(oF, res1, ln2, outp + (size_t)T_*H_,
                                            h2b, gatew, meta, tki, tkw);
  // 7. routing metadata (128-granular tiles)
  mx_scan<<<1, 256, 0, stream>>>(meta, perm, 7);
  mx_scatter<<<T_/256, 256, 0, stream>>>(tki, meta, perm, slot);
  // 8. MoE expert GEMMs
  mx_moe_w13<32><<<4096, 256, 0, stream>>>(h2b, w1b, w3b, Y1, perm, meta);
  mx_moe_w2k<16><<<2048, 256, 0, stream>>>(Y1, w2b, Y2, meta);
  // 9. combine weighted expert outputs -> out
  mx_combine<<<T_, 256, 0, stream>>>(Y2, slot, tkw, outp);
  (void)ws_size;
}